// Round 6
// baseline (686.872 us; speedup 1.0000x reference)
//
#include <hip/hip_runtime.h>
#include <cstdint>
#include <cstddef>

// GraphSAGE 2-layer fused pipeline, MI355X.
// Identity: segment_mean(x[src]) @ W == segment_mean((x@W)[src]) -> GEMM before gather.
// Inputs f32, output f32. Intermediates bf16-stored / f32-computed.
// R6: bucket build split into dst-range partition (782 bins, dense appends) +
//     per-bin LDS-staged bucket construction with coalesced int4 writeout.
//     Fixes 96 MB scattered-write amplification seen in R5 k_bucket counters.

#define CAP 64
#define BINSZ 128       // nodes per bin (dst >> 7)
#define BINCAP 3072     // max edges per bin; mean 2048, 22 sigma headroom

__device__ __forceinline__ float bf2f(unsigned short u) {
  return __uint_as_float(((unsigned int)u) << 16);
}
__device__ __forceinline__ unsigned short f2bf(float f) {
  unsigned int x = __float_as_uint(f);
  unsigned int r = (x + 0x7fffu + ((x >> 16) & 1u)) >> 16;  // RNE
  return (unsigned short)r;
}

// ---------------- phase 1: partition edges by dst bin ----------------
__global__ void k_part(const int* __restrict__ ei, int* __restrict__ cur,
                       unsigned int* __restrict__ part, int E) {
  int e = blockIdx.x * 256 + threadIdx.x;
  if (e >= E) return;
  int s = ei[e];        // src  (< 2^17)
  int d = ei[E + e];    // dst
  int bin = d >> 7;
  int pos = atomicAdd(&cur[bin], 1);
  if (pos < BINCAP)
    part[(size_t)bin * BINCAP + pos] = (unsigned)s | ((unsigned)(d & 127) << 17);
}

// ---------------- phase 2: per-bin bucket build in LDS, dense writeout ----------------
__global__ __launch_bounds__(256) void k_bucketC(
    const int* __restrict__ cur, const unsigned int* __restrict__ part,
    int* __restrict__ cnt, int* __restrict__ bucket) {
  __shared__ int lbkt[BINSZ * CAP];  // 32 KB
  __shared__ int ldeg[BINSZ];
  const int b = blockIdx.x, t = threadIdx.x;
  if (t < BINSZ) ldeg[t] = 0;
  __syncthreads();
  int m = cur[b]; if (m > BINCAP) m = BINCAP;
  for (int i = t; i < m; i += 256) {
    unsigned rec = part[(size_t)b * BINCAP + i];
    int s = rec & 0x1FFFF;
    int loc = rec >> 17;
    int p = atomicAdd(&ldeg[loc], 1);
    if (p < CAP) lbkt[loc * CAP + p] = s;
  }
  __syncthreads();
  if (t < BINSZ) cnt[b * BINSZ + t] = ldeg[t];
  const int4* s4 = (const int4*)lbkt;
  int4* d4 = (int4*)(bucket + (size_t)b * BINSZ * CAP);
  #pragma unroll 2
  for (int i = t; i < BINSZ * CAP / 4; i += 256) d4[i] = s4[i];
}

// ---------------- layer-1 GEMMs: xl = x@W1l, hroot = x@W1r + b1 ----------------
// 64 rows/block (8 waves x 8 rows). lane = output column.
__global__ __launch_bounds__(512) void k_gemm1(
    const float* __restrict__ x,
    const float* __restrict__ W1l,
    const float* __restrict__ W1r,
    const float* __restrict__ b1,
    unsigned short* __restrict__ xl,
    unsigned short* __restrict__ hroot,
    int Nn) {
  __shared__ float2 w[128 * 64];  // 64 KB: {W1l, W1r} interleaved, k-major
  for (int i = threadIdx.x; i < 128 * 64; i += 512) {
    w[i] = make_float2(W1l[i], W1r[i]);
  }
  __syncthreads();
  const int lane = threadIdx.x & 63;
  const int wid = threadIdx.x >> 6;
  int rowbase = blockIdx.x * 64 + wid * 8;
  rowbase = __builtin_amdgcn_readfirstlane(rowbase);  // force SGPR -> scalar x loads
  if (rowbase >= Nn) return;
  const float bj = b1[lane];

  const float* xr[8];
  #pragma unroll
  for (int r = 0; r < 8; ++r) {
    int rr = rowbase + r;
    if (rr > Nn - 1) rr = Nn - 1;
    xr[r] = x + (size_t)rr * 128;
  }

  float al[8], ar[8];
  #pragma unroll
  for (int r = 0; r < 8; ++r) { al[r] = 0.f; ar[r] = 0.f; }

  float4 nxt[8];
  #pragma unroll
  for (int r = 0; r < 8; ++r) nxt[r] = *(const float4*)(xr[r]);

  for (int k0 = 0; k0 < 128; k0 += 4) {
    float cur[8][4];
    #pragma unroll
    for (int r = 0; r < 8; ++r) {
      cur[r][0] = nxt[r].x; cur[r][1] = nxt[r].y;
      cur[r][2] = nxt[r].z; cur[r][3] = nxt[r].w;
    }
    if (k0 + 4 < 128) {
      #pragma unroll
      for (int r = 0; r < 8; ++r) nxt[r] = *(const float4*)(xr[r] + k0 + 4);
    }
    #pragma unroll
    for (int kk = 0; kk < 4; ++kk) {
      const float2 wv = w[(k0 + kk) * 64 + lane];
      #pragma unroll
      for (int r = 0; r < 8; ++r) {
        al[r] = fmaf(cur[r][kk], wv.x, al[r]);
        ar[r] = fmaf(cur[r][kk], wv.y, ar[r]);
      }
    }
  }

  #pragma unroll
  for (int r = 0; r < 8; ++r) {
    int rr = rowbase + r;
    if (rr < Nn) {
      xl[(size_t)rr * 64 + lane] = f2bf(al[r]);
      hroot[(size_t)rr * 64 + lane] = f2bf(ar[r] + bj);
    }
  }
}

// ---------------- layer-1 aggregate: h = relu(mean_nb(xl) + hroot), wave per node ----------------
__global__ __launch_bounds__(256) void k_agg1(
    const int* __restrict__ cnt, const int* __restrict__ bucket,
    const unsigned short* __restrict__ xl, const unsigned short* __restrict__ hroot,
    unsigned short* __restrict__ hbuf, int Nn) {
  const int lane = threadIdx.x & 63;
  const int gw = blockIdx.x * (blockDim.x >> 6) + (threadIdx.x >> 6);
  const int nw = gridDim.x * (blockDim.x >> 6);
  for (int n = gw; n < Nn; n += nw) {
    int c = cnt[n];
    int m = c < CAP ? c : CAP;
    int sidx = (lane < m) ? bucket[(size_t)n * CAP + lane] : 0;
    if ((unsigned)sidx >= (unsigned)Nn) sidx = 0;  // firewall
    float acc = 0.f;
    int i = 0;
    for (; i + 4 <= m; i += 4) {
      int s0 = __shfl(sidx, i, 64);
      int s1 = __shfl(sidx, i + 1, 64);
      int s2 = __shfl(sidx, i + 2, 64);
      int s3 = __shfl(sidx, i + 3, 64);
      float v0 = bf2f(xl[(size_t)s0 * 64 + lane]);
      float v1 = bf2f(xl[(size_t)s1 * 64 + lane]);
      float v2 = bf2f(xl[(size_t)s2 * 64 + lane]);
      float v3 = bf2f(xl[(size_t)s3 * 64 + lane]);
      acc += (v0 + v1) + (v2 + v3);
    }
    for (; i < m; ++i) {
      int s = __shfl(sidx, i, 64);
      acc += bf2f(xl[(size_t)s * 64 + lane]);
    }
    float dd = c > 0 ? (float)c : 1.f;
    float hv = acc / dd + bf2f(hroot[(size_t)n * 64 + lane]);
    hbuf[(size_t)n * 64 + lane] = f2bf(fmaxf(hv, 0.f));
  }
}

// ---------------- layer-2 GEMMs: hl = h@W2l, hr = h@W2r + b2 ; thread per row ----------------
__global__ __launch_bounds__(128) void k_gemm2(
    const unsigned short* __restrict__ hbuf,
    const float* __restrict__ W2l, const float* __restrict__ W2r,
    const float* __restrict__ b2,
    float* __restrict__ hl, float* __restrict__ hr, int Nn) {
  __shared__ float tile[128 * 65];  // +1 pad: conflict-free column reads
  const int t = threadIdx.x;
  const int rowbase = blockIdx.x * 128;
  for (int idx = t; idx < 128 * 64; idx += 128) {
    int r = idx >> 6, k = idx & 63;
    int n = rowbase + r;
    tile[r * 65 + k] = (n < Nn) ? bf2f(hbuf[(size_t)n * 64 + k]) : 0.f;
  }
  __syncthreads();
  int n = rowbase + t;
  if (n >= Nn) return;
  float al[7] = {0, 0, 0, 0, 0, 0, 0};
  float ar[7] = {0, 0, 0, 0, 0, 0, 0};
  for (int k = 0; k < 64; ++k) {
    float hv = tile[t * 65 + k];
    #pragma unroll
    for (int c = 0; c < 7; ++c) {
      al[c] = fmaf(hv, W2l[k * 7 + c], al[c]);
      ar[c] = fmaf(hv, W2r[k * 7 + c], ar[c]);
    }
  }
  #pragma unroll
  for (int c = 0; c < 7; ++c) {
    hl[(size_t)n * 7 + c] = al[c];
    hr[(size_t)n * 7 + c] = ar[c] + b2[c];
  }
}

// ---------------- layer-2 aggregate + log_softmax; 8 nodes/wave, 8 lanes/node ----------------
__global__ __launch_bounds__(256) void k_out(
    const int* __restrict__ cnt, const int* __restrict__ bucket,
    const float* __restrict__ hl, const float* __restrict__ hr,
    float* __restrict__ out, int Nn) {
  const int lane = threadIdx.x & 63;
  const int c = lane & 7;
  const int sub = lane >> 3;
  const int gw = blockIdx.x * (blockDim.x >> 6) + (threadIdx.x >> 6);
  const int n = gw * 8 + sub;
  if (n >= Nn) return;
  int cn = cnt[n];
  int m = cn < CAP ? cn : CAP;
  const bool act = (c < 7);
  float acc = 0.f;
  for (int e = 0; e < m; ++e) {
    int s = bucket[(size_t)n * CAP + e];  // group-uniform
    if ((unsigned)s >= (unsigned)Nn) s = 0;
    if (act) acc += hl[(size_t)s * 7 + c];
  }
  float dd = cn > 0 ? (float)cn : 1.f;
  float v = act ? (acc / dd + hr[(size_t)n * 7 + c]) : -INFINITY;
  float mx = v;
  mx = fmaxf(mx, __shfl_xor(mx, 1, 8));
  mx = fmaxf(mx, __shfl_xor(mx, 2, 8));
  mx = fmaxf(mx, __shfl_xor(mx, 4, 8));
  float ex = act ? expf(v - mx) : 0.f;
  float s2 = ex;
  s2 += __shfl_xor(s2, 1, 8);
  s2 += __shfl_xor(s2, 2, 8);
  s2 += __shfl_xor(s2, 4, 8);
  float res = v - mx - logf(s2);
  if (act) out[(size_t)n * 7 + c] = res;
}

static inline size_t alignup(size_t v) { return (v + 255) & ~(size_t)255; }

extern "C" void kernel_launch(void* const* d_in, const int* in_sizes, int n_in,
                              void* d_out, int out_size, void* d_ws, size_t ws_size,
                              hipStream_t stream) {
  const int N = in_sizes[0] / 128;
  const int E = in_sizes[1] / 2;
  const int NB = (N + BINSZ - 1) / BINSZ;   // 782 bins
  const int Np = NB * BINSZ;                // padded node count

  const float* x   = (const float*)d_in[0];
  const int*   ei  = (const int*)d_in[1];
  const float* W1l = (const float*)d_in[2];
  const float* W1r = (const float*)d_in[3];
  const float* b1  = (const float*)d_in[4];
  const float* W2l = (const float*)d_in[5];
  const float* W2r = (const float*)d_in[6];
  const float* b2  = (const float*)d_in[7];
  float* out = (float*)d_out;

  // workspace carve (~80 MB)
  char* p = (char*)d_ws;
  int* cur    = (int*)p;             p += alignup((size_t)NB * 4);
  int* cnt    = (int*)p;             p += alignup((size_t)Np * 4);
  unsigned int* part = (unsigned int*)p; p += alignup((size_t)NB * BINCAP * 4);
  int* bucket = (int*)p;             p += alignup((size_t)Np * CAP * 4);
  unsigned short* xl    = (unsigned short*)p; p += alignup((size_t)N * 64 * 2);
  unsigned short* hroot = (unsigned short*)p; p += alignup((size_t)N * 64 * 2);
  unsigned short* hbuf  = (unsigned short*)p; p += alignup((size_t)N * 64 * 2);
  float* hl  = (float*)p;            p += alignup((size_t)N * 7 * 4);
  float* hr  = (float*)p;            p += alignup((size_t)N * 7 * 4);

  hipMemsetAsync(cur, 0, (size_t)NB * 4, stream);

  dim3 b256(256);
  k_part<<<dim3((E + 255) / 256), b256, 0, stream>>>(ei, cur, part, E);
  k_bucketC<<<dim3(NB), b256, 0, stream>>>(cur, part, cnt, bucket);
  k_gemm1<<<dim3((N + 63) / 64), dim3(512), 0, stream>>>(x, W1l, W1r, b1, xl, hroot, N);
  k_agg1<<<dim3(2048), b256, 0, stream>>>(cnt, bucket, xl, hroot, hbuf, N);
  k_gemm2<<<dim3((N + 127) / 128), dim3(128), 0, stream>>>(hbuf, W2l, W2r, b2, hl, hr, N);
  const int waves_out = (N + 7) / 8;
  k_out<<<dim3((waves_out + 3) / 4), b256, 0, stream>>>(cnt, bucket, hl, hr, out, N);
}

// Round 7
// 537.593 us; speedup vs baseline: 1.2777x; 1.2777x over previous
//
#include <hip/hip_runtime.h>
#include <cstdint>
#include <cstddef>

// GraphSAGE 2-layer fused pipeline, MI355X.
// Identity: segment_mean(x[src]) @ W == segment_mean((x@W)[src]) -> GEMM before gather.
// Inputs f32, output f32. Intermediates bf16-stored / f32-computed.
// R7: neighbor-list build = contention-free counting sort:
//     k_hist (LDS histograms, no global atomics) -> k_scan (exact positions) ->
//     k_scat (LDS cursors, ~84B contiguous runs) -> k_bucketB (block-owned segment,
//     LDS-staged, coalesced int4 writeout). Fixes R6's 377us atomic-serialization
//     (2048 serialized ops/cursor) and R5's 96MB scattered-write amplification.

#define CAP 64
#define BINSZ 128        // nodes per bin (dst >> 7)
#define CH 16384         // edges per chunk block

__device__ __forceinline__ float bf2f(unsigned short u) {
  return __uint_as_float(((unsigned int)u) << 16);
}
__device__ __forceinline__ unsigned short f2bf(float f) {
  unsigned int x = __float_as_uint(f);
  unsigned int r = (x + 0x7fffu + ((x >> 16) & 1u)) >> 16;  // RNE
  return (unsigned short)r;
}

// ---------------- pass 1: per-chunk histogram over dst bins (no global atomics) ----------------
__global__ __launch_bounds__(256) void k_hist(const int* __restrict__ ei,
                                              int* __restrict__ hist,
                                              int E, int NB, int NCH) {
  __shared__ int lcnt[1024];
  const int c = blockIdx.x, t = threadIdx.x;
  for (int i = t; i < NB; i += 256) lcnt[i] = 0;
  __syncthreads();
  const int base = c * CH;
  const int end = min(base + CH, E);
  for (int e = base + t; e < end; e += 256) {
    int d = ei[E + e];
    atomicAdd(&lcnt[d >> 7], 1);  // LDS atomic
  }
  __syncthreads();
  for (int i = t; i < NB; i += 256) hist[(size_t)i * NCH + c] = lcnt[i];
}

// ---------------- pass 2: exact scatter bases (single block) ----------------
__global__ __launch_bounds__(256) void k_scan(int* __restrict__ hist,
                                              int* __restrict__ binbase,
                                              int NB, int NCH) {
  __shared__ int total[1024];
  const int t = threadIdx.x;
  for (int bin = t; bin < NB; bin += 256) {
    int run = 0;
    int* h = hist + (size_t)bin * NCH;
    for (int c = 0; c < NCH; ++c) { int v = h[c]; h[c] = run; run += v; }
    total[bin] = run;
  }
  __syncthreads();
  if (t == 0) {
    int run = 0;
    for (int i = 0; i < NB; ++i) { int v = total[i]; total[i] = run; run += v; }
    binbase[NB] = run;  // == E
  }
  __syncthreads();
  for (int bin = t; bin < NB; bin += 256) {
    int bb = total[bin];
    binbase[bin] = bb;
    int* h = hist + (size_t)bin * NCH;
    for (int c = 0; c < NCH; ++c) h[c] += bb;
  }
}

// ---------------- pass 3: scatter edges to bin-sorted array (LDS cursors only) ----------------
__global__ __launch_bounds__(256) void k_scat(const int* __restrict__ ei,
                                              const int* __restrict__ hist,
                                              unsigned int* __restrict__ part,
                                              int E, int NB, int NCH) {
  __shared__ int lcur[1024];
  const int c = blockIdx.x, t = threadIdx.x;
  for (int i = t; i < NB; i += 256) lcur[i] = hist[(size_t)i * NCH + c];
  __syncthreads();
  const int base = c * CH;
  const int end = min(base + CH, E);
  for (int e = base + t; e < end; e += 256) {
    int s = ei[e];        // src < 2^17
    int d = ei[E + e];    // dst
    int bin = d >> 7;
    int pos = atomicAdd(&lcur[bin], 1);  // LDS atomic; positions exact, no caps
    part[pos] = (unsigned)s | ((unsigned)(d & 127) << 17);
  }
}

// ---------------- pass 4: per-bin bucket build in LDS, coalesced writeout ----------------
__global__ __launch_bounds__(256) void k_bucketB(const int* __restrict__ binbase,
                                                 const unsigned int* __restrict__ part,
                                                 int* __restrict__ cnt,
                                                 int* __restrict__ bucket) {
  __shared__ int lbkt[BINSZ * CAP];  // 32 KB
  __shared__ int ldeg[BINSZ];
  const int b = blockIdx.x, t = threadIdx.x;
  if (t < BINSZ) ldeg[t] = 0;
  __syncthreads();
  const int e0 = binbase[b], e1 = binbase[b + 1];
  for (int i = e0 + t; i < e1; i += 256) {
    unsigned rec = part[i];
    int loc = rec >> 17;
    int p = atomicAdd(&ldeg[loc], 1);
    if (p < CAP) lbkt[loc * CAP + p] = (int)(rec & 0x1FFFFu);
  }
  __syncthreads();
  if (t < BINSZ) cnt[b * BINSZ + t] = ldeg[t];
  const int4* s4 = (const int4*)lbkt;
  int4* d4 = (int4*)(bucket + (size_t)b * BINSZ * CAP);
  #pragma unroll 2
  for (int i = t; i < BINSZ * CAP / 4; i += 256) d4[i] = s4[i];
}

// ---------------- layer-1 GEMMs: xl = x@W1l, hroot = x@W1r + b1 ----------------
// 64 rows/block (8 waves x 8 rows). lane = output column.
__global__ __launch_bounds__(512) void k_gemm1(
    const float* __restrict__ x,
    const float* __restrict__ W1l,
    const float* __restrict__ W1r,
    const float* __restrict__ b1,
    unsigned short* __restrict__ xl,
    unsigned short* __restrict__ hroot,
    int Nn) {
  __shared__ float2 w[128 * 64];  // 64 KB: {W1l, W1r} interleaved, k-major
  for (int i = threadIdx.x; i < 128 * 64; i += 512) {
    w[i] = make_float2(W1l[i], W1r[i]);
  }
  __syncthreads();
  const int lane = threadIdx.x & 63;
  const int wid = threadIdx.x >> 6;
  int rowbase = blockIdx.x * 64 + wid * 8;
  rowbase = __builtin_amdgcn_readfirstlane(rowbase);  // force SGPR -> scalar x loads
  if (rowbase >= Nn) return;
  const float bj = b1[lane];

  const float* xr[8];
  #pragma unroll
  for (int r = 0; r < 8; ++r) {
    int rr = rowbase + r;
    if (rr > Nn - 1) rr = Nn - 1;
    xr[r] = x + (size_t)rr * 128;
  }

  float al[8], ar[8];
  #pragma unroll
  for (int r = 0; r < 8; ++r) { al[r] = 0.f; ar[r] = 0.f; }

  float4 nxt[8];
  #pragma unroll
  for (int r = 0; r < 8; ++r) nxt[r] = *(const float4*)(xr[r]);

  for (int k0 = 0; k0 < 128; k0 += 4) {
    float cur[8][4];
    #pragma unroll
    for (int r = 0; r < 8; ++r) {
      cur[r][0] = nxt[r].x; cur[r][1] = nxt[r].y;
      cur[r][2] = nxt[r].z; cur[r][3] = nxt[r].w;
    }
    if (k0 + 4 < 128) {
      #pragma unroll
      for (int r = 0; r < 8; ++r) nxt[r] = *(const float4*)(xr[r] + k0 + 4);
    }
    #pragma unroll
    for (int kk = 0; kk < 4; ++kk) {
      const float2 wv = w[(k0 + kk) * 64 + lane];
      #pragma unroll
      for (int r = 0; r < 8; ++r) {
        al[r] = fmaf(cur[r][kk], wv.x, al[r]);
        ar[r] = fmaf(cur[r][kk], wv.y, ar[r]);
      }
    }
  }

  #pragma unroll
  for (int r = 0; r < 8; ++r) {
    int rr = rowbase + r;
    if (rr < Nn) {
      xl[(size_t)rr * 64 + lane] = f2bf(al[r]);
      hroot[(size_t)rr * 64 + lane] = f2bf(ar[r] + bj);
    }
  }
}

// ---------------- layer-1 aggregate: h = relu(mean_nb(xl) + hroot), wave per node ----------------
__global__ __launch_bounds__(256) void k_agg1(
    const int* __restrict__ cnt, const int* __restrict__ bucket,
    const unsigned short* __restrict__ xl, const unsigned short* __restrict__ hroot,
    unsigned short* __restrict__ hbuf, int Nn) {
  const int lane = threadIdx.x & 63;
  const int gw = blockIdx.x * (blockDim.x >> 6) + (threadIdx.x >> 6);
  const int nw = gridDim.x * (blockDim.x >> 6);
  for (int n = gw; n < Nn; n += nw) {
    int c = cnt[n];
    int m = c < CAP ? c : CAP;
    int sidx = (lane < m) ? bucket[(size_t)n * CAP + lane] : 0;
    if ((unsigned)sidx >= (unsigned)Nn) sidx = 0;  // firewall
    float acc = 0.f;
    int i = 0;
    for (; i + 4 <= m; i += 4) {
      int s0 = __shfl(sidx, i, 64);
      int s1 = __shfl(sidx, i + 1, 64);
      int s2 = __shfl(sidx, i + 2, 64);
      int s3 = __shfl(sidx, i + 3, 64);
      float v0 = bf2f(xl[(size_t)s0 * 64 + lane]);
      float v1 = bf2f(xl[(size_t)s1 * 64 + lane]);
      float v2 = bf2f(xl[(size_t)s2 * 64 + lane]);
      float v3 = bf2f(xl[(size_t)s3 * 64 + lane]);
      acc += (v0 + v1) + (v2 + v3);
    }
    for (; i < m; ++i) {
      int s = __shfl(sidx, i, 64);
      acc += bf2f(xl[(size_t)s * 64 + lane]);
    }
    float dd = c > 0 ? (float)c : 1.f;
    float hv = acc / dd + bf2f(hroot[(size_t)n * 64 + lane]);
    hbuf[(size_t)n * 64 + lane] = f2bf(fmaxf(hv, 0.f));
  }
}

// ---------------- layer-2 GEMMs: hl = h@W2l, hr = h@W2r + b2 ; thread per row ----------------
__global__ __launch_bounds__(128) void k_gemm2(
    const unsigned short* __restrict__ hbuf,
    const float* __restrict__ W2l, const float* __restrict__ W2r,
    const float* __restrict__ b2,
    float* __restrict__ hl, float* __restrict__ hr, int Nn) {
  __shared__ float tile[128 * 65];  // +1 pad: conflict-free column reads
  const int t = threadIdx.x;
  const int rowbase = blockIdx.x * 128;
  for (int idx = t; idx < 128 * 64; idx += 128) {
    int r = idx >> 6, k = idx & 63;
    int n = rowbase + r;
    tile[r * 65 + k] = (n < Nn) ? bf2f(hbuf[(size_t)n * 64 + k]) : 0.f;
  }
  __syncthreads();
  int n = rowbase + t;
  if (n >= Nn) return;
  float al[7] = {0, 0, 0, 0, 0, 0, 0};
  float ar[7] = {0, 0, 0, 0, 0, 0, 0};
  for (int k = 0; k < 64; ++k) {
    float hv = tile[t * 65 + k];
    #pragma unroll
    for (int c = 0; c < 7; ++c) {
      al[c] = fmaf(hv, W2l[k * 7 + c], al[c]);
      ar[c] = fmaf(hv, W2r[k * 7 + c], ar[c]);
    }
  }
  #pragma unroll
  for (int c = 0; c < 7; ++c) {
    hl[(size_t)n * 7 + c] = al[c];
    hr[(size_t)n * 7 + c] = ar[c] + b2[c];
  }
}

// ---------------- layer-2 aggregate + log_softmax; 8 nodes/wave, 8 lanes/node ----------------
__global__ __launch_bounds__(256) void k_out(
    const int* __restrict__ cnt, const int* __restrict__ bucket,
    const float* __restrict__ hl, const float* __restrict__ hr,
    float* __restrict__ out, int Nn) {
  const int lane = threadIdx.x & 63;
  const int c = lane & 7;
  const int sub = lane >> 3;
  const int gw = blockIdx.x * (blockDim.x >> 6) + (threadIdx.x >> 6);
  const int n = gw * 8 + sub;
  if (n >= Nn) return;
  int cn = cnt[n];
  int m = cn < CAP ? cn : CAP;
  const bool act = (c < 7);
  float acc = 0.f;
  for (int e = 0; e < m; ++e) {
    int s = bucket[(size_t)n * CAP + e];  // group-uniform
    if ((unsigned)s >= (unsigned)Nn) s = 0;
    if (act) acc += hl[(size_t)s * 7 + c];
  }
  float dd = cn > 0 ? (float)cn : 1.f;
  float v = act ? (acc / dd + hr[(size_t)n * 7 + c]) : -INFINITY;
  float mx = v;
  mx = fmaxf(mx, __shfl_xor(mx, 1, 8));
  mx = fmaxf(mx, __shfl_xor(mx, 2, 8));
  mx = fmaxf(mx, __shfl_xor(mx, 4, 8));
  float ex = act ? expf(v - mx) : 0.f;
  float s2 = ex;
  s2 += __shfl_xor(s2, 1, 8);
  s2 += __shfl_xor(s2, 2, 8);
  s2 += __shfl_xor(s2, 4, 8);
  float res = v - mx - logf(s2);
  if (act) out[(size_t)n * 7 + c] = res;
}

static inline size_t alignup(size_t v) { return (v + 255) & ~(size_t)255; }

extern "C" void kernel_launch(void* const* d_in, const int* in_sizes, int n_in,
                              void* d_out, int out_size, void* d_ws, size_t ws_size,
                              hipStream_t stream) {
  const int N = in_sizes[0] / 128;
  const int E = in_sizes[1] / 2;
  const int NB = (N + BINSZ - 1) / BINSZ;   // 782 bins
  const int Np = NB * BINSZ;                // padded node count
  const int NCH = (E + CH - 1) / CH;        // 98 chunks

  const float* x   = (const float*)d_in[0];
  const int*   ei  = (const int*)d_in[1];
  const float* W1l = (const float*)d_in[2];
  const float* W1r = (const float*)d_in[3];
  const float* b1  = (const float*)d_in[4];
  const float* W2l = (const float*)d_in[5];
  const float* W2r = (const float*)d_in[6];
  const float* b2  = (const float*)d_in[7];
  float* out = (float*)d_out;

  // workspace carve (~78 MB)
  char* p = (char*)d_ws;
  int* hist    = (int*)p;            p += alignup((size_t)NB * NCH * 4);
  int* binbase = (int*)p;            p += alignup((size_t)(NB + 1) * 4);
  unsigned int* part = (unsigned int*)p; p += alignup((size_t)E * 4);
  int* cnt    = (int*)p;             p += alignup((size_t)Np * 4);
  int* bucket = (int*)p;             p += alignup((size_t)Np * CAP * 4);
  unsigned short* xl    = (unsigned short*)p; p += alignup((size_t)N * 64 * 2);
  unsigned short* hroot = (unsigned short*)p; p += alignup((size_t)N * 64 * 2);
  unsigned short* hbuf  = (unsigned short*)p; p += alignup((size_t)N * 64 * 2);
  float* hl  = (float*)p;            p += alignup((size_t)N * 7 * 4);
  float* hr  = (float*)p;            p += alignup((size_t)N * 7 * 4);

  dim3 b256(256);
  k_hist<<<dim3(NCH), b256, 0, stream>>>(ei, hist, E, NB, NCH);
  k_scan<<<dim3(1), b256, 0, stream>>>(hist, binbase, NB, NCH);
  k_scat<<<dim3(NCH), b256, 0, stream>>>(ei, hist, part, E, NB, NCH);
  k_bucketB<<<dim3(NB), b256, 0, stream>>>(binbase, part, cnt, bucket);
  k_gemm1<<<dim3((N + 63) / 64), dim3(512), 0, stream>>>(x, W1l, W1r, b1, xl, hroot, N);
  k_agg1<<<dim3(2048), b256, 0, stream>>>(cnt, bucket, xl, hroot, hbuf, N);
  k_gemm2<<<dim3((N + 127) / 128), dim3(128), 0, stream>>>(hbuf, W2l, W2r, b2, hl, hr, N);
  const int waves_out = (N + 7) / 8;
  k_out<<<dim3((waves_out + 3) / 4), b256, 0, stream>>>(cnt, bucket, hl, hr, out, N);
}

// Round 8
// 359.626 us; speedup vs baseline: 1.9100x; 1.4949x over previous
//
#include <hip/hip_runtime.h>
#include <cstdint>
#include <cstddef>

// GraphSAGE 2-layer fused pipeline, MI355X.
// Identity: segment_mean(x[src]) @ W == segment_mean((x@W)[src]) -> GEMM before gather.
// Inputs f32, output f32. Intermediates bf16-stored / f32-computed.
// R8: counting-sort scan parallelized: k_scanA (1 wave/bin, shfl scan of 98 chunk
//     counts) + k_scanB (1 wave over 782 bin totals); "+binbase" folded into k_scat
//     cursor load. Replaces R7's single-block k_scan (190us of un-hidden latency,
//     occupancy 0.045%).

#define CAP 64
#define BINSZ 128        // nodes per bin (dst >> 7)
#define CH 16384         // edges per chunk block

__device__ __forceinline__ float bf2f(unsigned short u) {
  return __uint_as_float(((unsigned int)u) << 16);
}
__device__ __forceinline__ unsigned short f2bf(float f) {
  unsigned int x = __float_as_uint(f);
  unsigned int r = (x + 0x7fffu + ((x >> 16) & 1u)) >> 16;  // RNE
  return (unsigned short)r;
}

// ---------------- pass 1: per-chunk histogram over dst bins (no global atomics) ----------------
__global__ __launch_bounds__(256) void k_hist(const int* __restrict__ ei,
                                              int* __restrict__ hist,
                                              int E, int NB, int NCH) {
  __shared__ int lcnt[1024];
  const int c = blockIdx.x, t = threadIdx.x;
  for (int i = t; i < NB; i += 256) lcnt[i] = 0;
  __syncthreads();
  const int base = c * CH;
  const int end = min(base + CH, E);
  for (int e = base + t; e < end; e += 256) {
    int d = ei[E + e];
    atomicAdd(&lcnt[d >> 7], 1);  // LDS atomic
  }
  __syncthreads();
  for (int i = t; i < NB; i += 256) hist[(size_t)i * NCH + c] = lcnt[i];
}

// ---------------- pass 2a: per-bin exclusive scan over chunks (1 wave/bin) ----------------
__global__ __launch_bounds__(256) void k_scanA(int* __restrict__ hist,
                                               int* __restrict__ tot,
                                               int NB, int NCH) {
  const int lane = threadIdx.x & 63;
  const int bin = blockIdx.x * 4 + (threadIdx.x >> 6);
  if (bin >= NB) return;
  int* h = hist + (size_t)bin * NCH;
  int carry = 0;
  for (int base = 0; base < NCH; base += 64) {
    int i = base + lane;
    int v = (i < NCH) ? h[i] : 0;
    int incl = v;
    #pragma unroll
    for (int d = 1; d < 64; d <<= 1) {
      int t = __shfl_up(incl, d, 64);
      if (lane >= d) incl += t;
    }
    if (i < NCH) h[i] = carry + incl - v;  // exclusive prefix within bin
    carry += __shfl(incl, 63, 64);
  }
  if (lane == 0) tot[bin] = carry;
}

// ---------------- pass 2b: scan bin totals -> binbase (1 wave) ----------------
__global__ __launch_bounds__(64) void k_scanB(const int* __restrict__ tot,
                                              int* __restrict__ binbase, int NB) {
  const int lane = threadIdx.x;
  int carry = 0;
  for (int base = 0; base < NB; base += 64) {
    int i = base + lane;
    int v = (i < NB) ? tot[i] : 0;
    int incl = v;
    #pragma unroll
    for (int d = 1; d < 64; d <<= 1) {
      int t = __shfl_up(incl, d, 64);
      if (lane >= d) incl += t;
    }
    if (i < NB) binbase[i] = carry + incl - v;
    carry += __shfl(incl, 63, 64);
  }
  if (lane == 0) binbase[NB] = carry;  // == E
}

// ---------------- pass 3: scatter edges to bin-sorted array (LDS cursors only) ----------------
__global__ __launch_bounds__(256) void k_scat(const int* __restrict__ ei,
                                              const int* __restrict__ hist,
                                              const int* __restrict__ binbase,
                                              unsigned int* __restrict__ part,
                                              int E, int NB, int NCH) {
  __shared__ int lcur[1024];
  const int c = blockIdx.x, t = threadIdx.x;
  for (int i = t; i < NB; i += 256)
    lcur[i] = hist[(size_t)i * NCH + c] + binbase[i];
  __syncthreads();
  const int base = c * CH;
  const int end = min(base + CH, E);
  for (int e = base + t; e < end; e += 256) {
    int s = ei[e];        // src < 2^17
    int d = ei[E + e];    // dst
    int bin = d >> 7;
    int pos = atomicAdd(&lcur[bin], 1);  // LDS atomic; positions exact
    part[pos] = (unsigned)s | ((unsigned)(d & 127) << 17);
  }
}

// ---------------- pass 4: per-bin bucket build in LDS, coalesced writeout ----------------
__global__ __launch_bounds__(256) void k_bucketB(const int* __restrict__ binbase,
                                                 const unsigned int* __restrict__ part,
                                                 int* __restrict__ cnt,
                                                 int* __restrict__ bucket) {
  __shared__ int lbkt[BINSZ * CAP];  // 32 KB
  __shared__ int ldeg[BINSZ];
  const int b = blockIdx.x, t = threadIdx.x;
  if (t < BINSZ) ldeg[t] = 0;
  __syncthreads();
  const int e0 = binbase[b], e1 = binbase[b + 1];
  for (int i = e0 + t; i < e1; i += 256) {
    unsigned rec = part[i];
    int loc = rec >> 17;
    int p = atomicAdd(&ldeg[loc], 1);
    if (p < CAP) lbkt[loc * CAP + p] = (int)(rec & 0x1FFFFu);
  }
  __syncthreads();
  if (t < BINSZ) cnt[b * BINSZ + t] = ldeg[t];
  const int4* s4 = (const int4*)lbkt;
  int4* d4 = (int4*)(bucket + (size_t)b * BINSZ * CAP);
  #pragma unroll 2
  for (int i = t; i < BINSZ * CAP / 4; i += 256) d4[i] = s4[i];
}

// ---------------- layer-1 GEMMs: xl = x@W1l, hroot = x@W1r + b1 ----------------
// 64 rows/block (8 waves x 8 rows). lane = output column.
__global__ __launch_bounds__(512) void k_gemm1(
    const float* __restrict__ x,
    const float* __restrict__ W1l,
    const float* __restrict__ W1r,
    const float* __restrict__ b1,
    unsigned short* __restrict__ xl,
    unsigned short* __restrict__ hroot,
    int Nn) {
  __shared__ float2 w[128 * 64];  // 64 KB: {W1l, W1r} interleaved, k-major
  for (int i = threadIdx.x; i < 128 * 64; i += 512) {
    w[i] = make_float2(W1l[i], W1r[i]);
  }
  __syncthreads();
  const int lane = threadIdx.x & 63;
  const int wid = threadIdx.x >> 6;
  int rowbase = blockIdx.x * 64 + wid * 8;
  rowbase = __builtin_amdgcn_readfirstlane(rowbase);  // force SGPR -> scalar x loads
  if (rowbase >= Nn) return;
  const float bj = b1[lane];

  const float* xr[8];
  #pragma unroll
  for (int r = 0; r < 8; ++r) {
    int rr = rowbase + r;
    if (rr > Nn - 1) rr = Nn - 1;
    xr[r] = x + (size_t)rr * 128;
  }

  float al[8], ar[8];
  #pragma unroll
  for (int r = 0; r < 8; ++r) { al[r] = 0.f; ar[r] = 0.f; }

  float4 nxt[8];
  #pragma unroll
  for (int r = 0; r < 8; ++r) nxt[r] = *(const float4*)(xr[r]);

  for (int k0 = 0; k0 < 128; k0 += 4) {
    float cur[8][4];
    #pragma unroll
    for (int r = 0; r < 8; ++r) {
      cur[r][0] = nxt[r].x; cur[r][1] = nxt[r].y;
      cur[r][2] = nxt[r].z; cur[r][3] = nxt[r].w;
    }
    if (k0 + 4 < 128) {
      #pragma unroll
      for (int r = 0; r < 8; ++r) nxt[r] = *(const float4*)(xr[r] + k0 + 4);
    }
    #pragma unroll
    for (int kk = 0; kk < 4; ++kk) {
      const float2 wv = w[(k0 + kk) * 64 + lane];
      #pragma unroll
      for (int r = 0; r < 8; ++r) {
        al[r] = fmaf(cur[r][kk], wv.x, al[r]);
        ar[r] = fmaf(cur[r][kk], wv.y, ar[r]);
      }
    }
  }

  #pragma unroll
  for (int r = 0; r < 8; ++r) {
    int rr = rowbase + r;
    if (rr < Nn) {
      xl[(size_t)rr * 64 + lane] = f2bf(al[r]);
      hroot[(size_t)rr * 64 + lane] = f2bf(ar[r] + bj);
    }
  }
}

// ---------------- layer-1 aggregate: h = relu(mean_nb(xl) + hroot), wave per node ----------------
__global__ __launch_bounds__(256) void k_agg1(
    const int* __restrict__ cnt, const int* __restrict__ bucket,
    const unsigned short* __restrict__ xl, const unsigned short* __restrict__ hroot,
    unsigned short* __restrict__ hbuf, int Nn) {
  const int lane = threadIdx.x & 63;
  const int gw = blockIdx.x * (blockDim.x >> 6) + (threadIdx.x >> 6);
  const int nw = gridDim.x * (blockDim.x >> 6);
  for (int n = gw; n < Nn; n += nw) {
    int c = cnt[n];
    int m = c < CAP ? c : CAP;
    int sidx = (lane < m) ? bucket[(size_t)n * CAP + lane] : 0;
    if ((unsigned)sidx >= (unsigned)Nn) sidx = 0;  // firewall
    float acc = 0.f;
    int i = 0;
    for (; i + 4 <= m; i += 4) {
      int s0 = __shfl(sidx, i, 64);
      int s1 = __shfl(sidx, i + 1, 64);
      int s2 = __shfl(sidx, i + 2, 64);
      int s3 = __shfl(sidx, i + 3, 64);
      float v0 = bf2f(xl[(size_t)s0 * 64 + lane]);
      float v1 = bf2f(xl[(size_t)s1 * 64 + lane]);
      float v2 = bf2f(xl[(size_t)s2 * 64 + lane]);
      float v3 = bf2f(xl[(size_t)s3 * 64 + lane]);
      acc += (v0 + v1) + (v2 + v3);
    }
    for (; i < m; ++i) {
      int s = __shfl(sidx, i, 64);
      acc += bf2f(xl[(size_t)s * 64 + lane]);
    }
    float dd = c > 0 ? (float)c : 1.f;
    float hv = acc / dd + bf2f(hroot[(size_t)n * 64 + lane]);
    hbuf[(size_t)n * 64 + lane] = f2bf(fmaxf(hv, 0.f));
  }
}

// ---------------- layer-2 GEMMs: hl = h@W2l, hr = h@W2r + b2 ; thread per row ----------------
__global__ __launch_bounds__(128) void k_gemm2(
    const unsigned short* __restrict__ hbuf,
    const float* __restrict__ W2l, const float* __restrict__ W2r,
    const float* __restrict__ b2,
    float* __restrict__ hl, float* __restrict__ hr, int Nn) {
  __shared__ float tile[128 * 65];  // +1 pad: conflict-free column reads
  const int t = threadIdx.x;
  const int rowbase = blockIdx.x * 128;
  for (int idx = t; idx < 128 * 64; idx += 128) {
    int r = idx >> 6, k = idx & 63;
    int n = rowbase + r;
    tile[r * 65 + k] = (n < Nn) ? bf2f(hbuf[(size_t)n * 64 + k]) : 0.f;
  }
  __syncthreads();
  int n = rowbase + t;
  if (n >= Nn) return;
  float al[7] = {0, 0, 0, 0, 0, 0, 0};
  float ar[7] = {0, 0, 0, 0, 0, 0, 0};
  for (int k = 0; k < 64; ++k) {
    float hv = tile[t * 65 + k];
    #pragma unroll
    for (int c = 0; c < 7; ++c) {
      al[c] = fmaf(hv, W2l[k * 7 + c], al[c]);
      ar[c] = fmaf(hv, W2r[k * 7 + c], ar[c]);
    }
  }
  #pragma unroll
  for (int c = 0; c < 7; ++c) {
    hl[(size_t)n * 7 + c] = al[c];
    hr[(size_t)n * 7 + c] = ar[c] + b2[c];
  }
}

// ---------------- layer-2 aggregate + log_softmax; 8 nodes/wave, 8 lanes/node ----------------
__global__ __launch_bounds__(256) void k_out(
    const int* __restrict__ cnt, const int* __restrict__ bucket,
    const float* __restrict__ hl, const float* __restrict__ hr,
    float* __restrict__ out, int Nn) {
  const int lane = threadIdx.x & 63;
  const int c = lane & 7;
  const int sub = lane >> 3;
  const int gw = blockIdx.x * (blockDim.x >> 6) + (threadIdx.x >> 6);
  const int n = gw * 8 + sub;
  if (n >= Nn) return;
  int cn = cnt[n];
  int m = cn < CAP ? cn : CAP;
  const bool act = (c < 7);
  float acc = 0.f;
  for (int e = 0; e < m; ++e) {
    int s = bucket[(size_t)n * CAP + e];  // group-uniform
    if ((unsigned)s >= (unsigned)Nn) s = 0;
    if (act) acc += hl[(size_t)s * 7 + c];
  }
  float dd = cn > 0 ? (float)cn : 1.f;
  float v = act ? (acc / dd + hr[(size_t)n * 7 + c]) : -INFINITY;
  float mx = v;
  mx = fmaxf(mx, __shfl_xor(mx, 1, 8));
  mx = fmaxf(mx, __shfl_xor(mx, 2, 8));
  mx = fmaxf(mx, __shfl_xor(mx, 4, 8));
  float ex = act ? expf(v - mx) : 0.f;
  float s2 = ex;
  s2 += __shfl_xor(s2, 1, 8);
  s2 += __shfl_xor(s2, 2, 8);
  s2 += __shfl_xor(s2, 4, 8);
  float res = v - mx - logf(s2);
  if (act) out[(size_t)n * 7 + c] = res;
}

static inline size_t alignup(size_t v) { return (v + 255) & ~(size_t)255; }

extern "C" void kernel_launch(void* const* d_in, const int* in_sizes, int n_in,
                              void* d_out, int out_size, void* d_ws, size_t ws_size,
                              hipStream_t stream) {
  const int N = in_sizes[0] / 128;
  const int E = in_sizes[1] / 2;
  const int NB = (N + BINSZ - 1) / BINSZ;   // 782 bins
  const int Np = NB * BINSZ;                // padded node count
  const int NCH = (E + CH - 1) / CH;        // 98 chunks

  const float* x   = (const float*)d_in[0];
  const int*   ei  = (const int*)d_in[1];
  const float* W1l = (const float*)d_in[2];
  const float* W1r = (const float*)d_in[3];
  const float* b1  = (const float*)d_in[4];
  const float* W2l = (const float*)d_in[5];
  const float* W2r = (const float*)d_in[6];
  const float* b2  = (const float*)d_in[7];
  float* out = (float*)d_out;

  // workspace carve (~78 MB)
  char* p = (char*)d_ws;
  int* hist    = (int*)p;            p += alignup((size_t)NB * NCH * 4);
  int* tot     = (int*)p;            p += alignup((size_t)NB * 4);
  int* binbase = (int*)p;            p += alignup((size_t)(NB + 1) * 4);
  unsigned int* part = (unsigned int*)p; p += alignup((size_t)E * 4);
  int* cnt    = (int*)p;             p += alignup((size_t)Np * 4);
  int* bucket = (int*)p;             p += alignup((size_t)Np * CAP * 4);
  unsigned short* xl    = (unsigned short*)p; p += alignup((size_t)N * 64 * 2);
  unsigned short* hroot = (unsigned short*)p; p += alignup((size_t)N * 64 * 2);
  unsigned short* hbuf  = (unsigned short*)p; p += alignup((size_t)N * 64 * 2);
  float* hl  = (float*)p;            p += alignup((size_t)N * 7 * 4);
  float* hr  = (float*)p;            p += alignup((size_t)N * 7 * 4);

  dim3 b256(256);
  k_hist<<<dim3(NCH), b256, 0, stream>>>(ei, hist, E, NB, NCH);
  k_scanA<<<dim3((NB + 3) / 4), b256, 0, stream>>>(hist, tot, NB, NCH);
  k_scanB<<<dim3(1), dim3(64), 0, stream>>>(tot, binbase, NB);
  k_scat<<<dim3(NCH), b256, 0, stream>>>(ei, hist, binbase, part, E, NB, NCH);
  k_bucketB<<<dim3(NB), b256, 0, stream>>>(binbase, part, cnt, bucket);
  k_gemm1<<<dim3((N + 63) / 64), dim3(512), 0, stream>>>(x, W1l, W1r, b1, xl, hroot, N);
  k_agg1<<<dim3(2048), b256, 0, stream>>>(cnt, bucket, xl, hroot, hbuf, N);
  k_gemm2<<<dim3((N + 127) / 128), dim3(128), 0, stream>>>(hbuf, W2l, W2r, b2, hl, hr, N);
  const int waves_out = (N + 7) / 8;
  k_out<<<dim3((waves_out + 3) / 4), b256, 0, stream>>>(cnt, bucket, hl, hr, out, N);
}

// Round 9
// 329.016 us; speedup vs baseline: 2.0877x; 1.0930x over previous
//
#include <hip/hip_runtime.h>
#include <cstdint>
#include <cstddef>

// GraphSAGE 2-layer fused pipeline, MI355X.
// Identity: segment_mean(x[src]) @ W == segment_mean((x@W)[src]) -> GEMM before gather.
// Inputs f32, output f32. Intermediates bf16-stored / f32-computed.
// R9: k_gemm1 rebuilt on the canonical LDS-staged pattern. R8's readfirstlane
//     s_load trick serialized on lgkmcnt(0) (SMEM is out-of-order on that counter,
//     so every consume drained the prefetch -> VALUBusy 21%). Now: x-tile staged
//     to LDS once (coalesced float4), weights packed bf16x2 (32 KB), hot loop is
//     pure DS (in-order, partial lgkmcnt waits) + FMA.

#define CAP 64
#define BINSZ 128        // nodes per bin (dst >> 7)
#define CH 16384         // edges per chunk block

__device__ __forceinline__ float bf2f(unsigned short u) {
  return __uint_as_float(((unsigned int)u) << 16);
}
__device__ __forceinline__ unsigned short f2bf(float f) {
  unsigned int x = __float_as_uint(f);
  unsigned int r = (x + 0x7fffu + ((x >> 16) & 1u)) >> 16;  // RNE
  return (unsigned short)r;
}

// ---------------- pass 1: per-chunk histogram over dst bins (no global atomics) ----------------
__global__ __launch_bounds__(256) void k_hist(const int* __restrict__ ei,
                                              int* __restrict__ hist,
                                              int E, int NB, int NCH) {
  __shared__ int lcnt[1024];
  const int c = blockIdx.x, t = threadIdx.x;
  for (int i = t; i < NB; i += 256) lcnt[i] = 0;
  __syncthreads();
  const int base = c * CH;
  const int end = min(base + CH, E);
  for (int e = base + t; e < end; e += 256) {
    int d = ei[E + e];
    atomicAdd(&lcnt[d >> 7], 1);  // LDS atomic
  }
  __syncthreads();
  for (int i = t; i < NB; i += 256) hist[(size_t)i * NCH + c] = lcnt[i];
}

// ---------------- pass 2a: per-bin exclusive scan over chunks (1 wave/bin) ----------------
__global__ __launch_bounds__(256) void k_scanA(int* __restrict__ hist,
                                               int* __restrict__ tot,
                                               int NB, int NCH) {
  const int lane = threadIdx.x & 63;
  const int bin = blockIdx.x * 4 + (threadIdx.x >> 6);
  if (bin >= NB) return;
  int* h = hist + (size_t)bin * NCH;
  int carry = 0;
  for (int base = 0; base < NCH; base += 64) {
    int i = base + lane;
    int v = (i < NCH) ? h[i] : 0;
    int incl = v;
    #pragma unroll
    for (int d = 1; d < 64; d <<= 1) {
      int t = __shfl_up(incl, d, 64);
      if (lane >= d) incl += t;
    }
    if (i < NCH) h[i] = carry + incl - v;  // exclusive prefix within bin
    carry += __shfl(incl, 63, 64);
  }
  if (lane == 0) tot[bin] = carry;
}

// ---------------- pass 2b: scan bin totals -> binbase (1 wave) ----------------
__global__ __launch_bounds__(64) void k_scanB(const int* __restrict__ tot,
                                              int* __restrict__ binbase, int NB) {
  const int lane = threadIdx.x;
  int carry = 0;
  for (int base = 0; base < NB; base += 64) {
    int i = base + lane;
    int v = (i < NB) ? tot[i] : 0;
    int incl = v;
    #pragma unroll
    for (int d = 1; d < 64; d <<= 1) {
      int t = __shfl_up(incl, d, 64);
      if (lane >= d) incl += t;
    }
    if (i < NB) binbase[i] = carry + incl - v;
    carry += __shfl(incl, 63, 64);
  }
  if (lane == 0) binbase[NB] = carry;  // == E
}

// ---------------- pass 3: scatter edges to bin-sorted array (LDS cursors only) ----------------
__global__ __launch_bounds__(256) void k_scat(const int* __restrict__ ei,
                                              const int* __restrict__ hist,
                                              const int* __restrict__ binbase,
                                              unsigned int* __restrict__ part,
                                              int E, int NB, int NCH) {
  __shared__ int lcur[1024];
  const int c = blockIdx.x, t = threadIdx.x;
  for (int i = t; i < NB; i += 256)
    lcur[i] = hist[(size_t)i * NCH + c] + binbase[i];
  __syncthreads();
  const int base = c * CH;
  const int end = min(base + CH, E);
  for (int e = base + t; e < end; e += 256) {
    int s = ei[e];        // src < 2^17
    int d = ei[E + e];    // dst
    int bin = d >> 7;
    int pos = atomicAdd(&lcur[bin], 1);  // LDS atomic; positions exact
    part[pos] = (unsigned)s | ((unsigned)(d & 127) << 17);
  }
}

// ---------------- pass 4: per-bin bucket build in LDS, coalesced writeout ----------------
__global__ __launch_bounds__(256) void k_bucketB(const int* __restrict__ binbase,
                                                 const unsigned int* __restrict__ part,
                                                 int* __restrict__ cnt,
                                                 int* __restrict__ bucket) {
  __shared__ int lbkt[BINSZ * CAP];  // 32 KB
  __shared__ int ldeg[BINSZ];
  const int b = blockIdx.x, t = threadIdx.x;
  if (t < BINSZ) ldeg[t] = 0;
  __syncthreads();
  const int e0 = binbase[b], e1 = binbase[b + 1];
  for (int i = e0 + t; i < e1; i += 256) {
    unsigned rec = part[i];
    int loc = rec >> 17;
    int p = atomicAdd(&ldeg[loc], 1);
    if (p < CAP) lbkt[loc * CAP + p] = (int)(rec & 0x1FFFFu);
  }
  __syncthreads();
  if (t < BINSZ) cnt[b * BINSZ + t] = ldeg[t];
  const int4* s4 = (const int4*)lbkt;
  int4* d4 = (int4*)(bucket + (size_t)b * BINSZ * CAP);
  #pragma unroll 2
  for (int i = t; i < BINSZ * CAP / 4; i += 256) d4[i] = s4[i];
}

// ---------------- layer-1 GEMMs: xl = x@W1l, hroot = x@W1r + b1 ----------------
// 64 rows/block, 8 waves x 8 rows. lane = output column. Pure-DS hot loop.
__global__ __launch_bounds__(512) void k_gemm1(
    const float* __restrict__ x,
    const float* __restrict__ W1l,
    const float* __restrict__ W1r,
    const float* __restrict__ b1,
    unsigned short* __restrict__ xl,
    unsigned short* __restrict__ hroot,
    int Nn) {
  __shared__ unsigned int wp[128 * 64];  // 32 KB: bf16 pair {lo: W1l, hi: W1r}, k-major
  __shared__ float xt[64 * 128];         // 32 KB: x-tile, row-major
  const int t = threadIdx.x;
  const int rowbase = blockIdx.x * 64;
  for (int i = t; i < 128 * 64; i += 512)
    wp[i] = (unsigned)f2bf(W1l[i]) | ((unsigned)f2bf(W1r[i]) << 16);
  {
    const int nrow = Nn - rowbase;  // >=1
    for (int i = t; i < 2048; i += 512) {    // 2048 float4 = 32 KB
      int r = i >> 5;                        // 32 float4 per row
      int kq = (i & 31) << 2;
      float4 v = (r < nrow) ? *(const float4*)(x + (size_t)(rowbase + r) * 128 + kq)
                            : make_float4(0.f, 0.f, 0.f, 0.f);
      *(float4*)&xt[r * 128 + kq] = v;
    }
  }
  __syncthreads();
  const int lane = t & 63;
  const int r0 = (t >> 6) * 8;

  float al[8], ar[8];
  #pragma unroll
  for (int r = 0; r < 8; ++r) { al[r] = 0.f; ar[r] = 0.f; }

  for (int k0 = 0; k0 < 128; k0 += 4) {
    float4 xv[8];
    #pragma unroll
    for (int r = 0; r < 8; ++r)
      xv[r] = *(const float4*)&xt[(r0 + r) * 128 + k0];  // wave-uniform addr -> broadcast
    #pragma unroll
    for (int kk = 0; kk < 4; ++kk) {
      const unsigned wv = wp[(k0 + kk) * 64 + lane];
      const float wlv = __uint_as_float(wv << 16);
      const float wrv = __uint_as_float(wv & 0xFFFF0000u);
      #pragma unroll
      for (int r = 0; r < 8; ++r) {
        const float xs = ((const float*)&xv[r])[kk];
        al[r] = fmaf(xs, wlv, al[r]);
        ar[r] = fmaf(xs, wrv, ar[r]);
      }
    }
  }

  const float bj = b1[lane];
  #pragma unroll
  for (int r = 0; r < 8; ++r) {
    int rr = rowbase + r0 + r;
    if (rr < Nn) {
      xl[(size_t)rr * 64 + lane] = f2bf(al[r]);
      hroot[(size_t)rr * 64 + lane] = f2bf(ar[r] + bj);
    }
  }
}

// ---------------- layer-1 aggregate: h = relu(mean_nb(xl) + hroot), wave per node ----------------
__global__ __launch_bounds__(256) void k_agg1(
    const int* __restrict__ cnt, const int* __restrict__ bucket,
    const unsigned short* __restrict__ xl, const unsigned short* __restrict__ hroot,
    unsigned short* __restrict__ hbuf, int Nn) {
  const int lane = threadIdx.x & 63;
  const int gw = blockIdx.x * (blockDim.x >> 6) + (threadIdx.x >> 6);
  const int nw = gridDim.x * (blockDim.x >> 6);
  for (int n = gw; n < Nn; n += nw) {
    int c = cnt[n];
    int m = c < CAP ? c : CAP;
    int sidx = (lane < m) ? bucket[(size_t)n * CAP + lane] : 0;
    if ((unsigned)sidx >= (unsigned)Nn) sidx = 0;  // firewall
    float acc = 0.f;
    int i = 0;
    for (; i + 4 <= m; i += 4) {
      int s0 = __shfl(sidx, i, 64);
      int s1 = __shfl(sidx, i + 1, 64);
      int s2 = __shfl(sidx, i + 2, 64);
      int s3 = __shfl(sidx, i + 3, 64);
      float v0 = bf2f(xl[(size_t)s0 * 64 + lane]);
      float v1 = bf2f(xl[(size_t)s1 * 64 + lane]);
      float v2 = bf2f(xl[(size_t)s2 * 64 + lane]);
      float v3 = bf2f(xl[(size_t)s3 * 64 + lane]);
      acc += (v0 + v1) + (v2 + v3);
    }
    for (; i < m; ++i) {
      int s = __shfl(sidx, i, 64);
      acc += bf2f(xl[(size_t)s * 64 + lane]);
    }
    float dd = c > 0 ? (float)c : 1.f;
    float hv = acc / dd + bf2f(hroot[(size_t)n * 64 + lane]);
    hbuf[(size_t)n * 64 + lane] = f2bf(fmaxf(hv, 0.f));
  }
}

// ---------------- layer-2 GEMMs: hl = h@W2l, hr = h@W2r + b2 ; thread per row ----------------
__global__ __launch_bounds__(128) void k_gemm2(
    const unsigned short* __restrict__ hbuf,
    const float* __restrict__ W2l, const float* __restrict__ W2r,
    const float* __restrict__ b2,
    float* __restrict__ hl, float* __restrict__ hr, int Nn) {
  __shared__ float tile[128 * 65];  // +1 pad: conflict-free column reads
  const int t = threadIdx.x;
  const int rowbase = blockIdx.x * 128;
  for (int idx = t; idx < 128 * 64; idx += 128) {
    int r = idx >> 6, k = idx & 63;
    int n = rowbase + r;
    tile[r * 65 + k] = (n < Nn) ? bf2f(hbuf[(size_t)n * 64 + k]) : 0.f;
  }
  __syncthreads();
  int n = rowbase + t;
  if (n >= Nn) return;
  float al[7] = {0, 0, 0, 0, 0, 0, 0};
  float ar[7] = {0, 0, 0, 0, 0, 0, 0};
  for (int k = 0; k < 64; ++k) {
    float hv = tile[t * 65 + k];
    #pragma unroll
    for (int c = 0; c < 7; ++c) {
      al[c] = fmaf(hv, W2l[k * 7 + c], al[c]);
      ar[c] = fmaf(hv, W2r[k * 7 + c], ar[c]);
    }
  }
  #pragma unroll
  for (int c = 0; c < 7; ++c) {
    hl[(size_t)n * 7 + c] = al[c];
    hr[(size_t)n * 7 + c] = ar[c] + b2[c];
  }
}

// ---------------- layer-2 aggregate + log_softmax; 8 nodes/wave, 8 lanes/node ----------------
__global__ __launch_bounds__(256) void k_out(
    const int* __restrict__ cnt, const int* __restrict__ bucket,
    const float* __restrict__ hl, const float* __restrict__ hr,
    float* __restrict__ out, int Nn) {
  const int lane = threadIdx.x & 63;
  const int c = lane & 7;
  const int sub = lane >> 3;
  const int gw = blockIdx.x * (blockDim.x >> 6) + (threadIdx.x >> 6);
  const int n = gw * 8 + sub;
  if (n >= Nn) return;
  int cn = cnt[n];
  int m = cn < CAP ? cn : CAP;
  const bool act = (c < 7);
  float acc = 0.f;
  for (int e = 0; e < m; ++e) {
    int s = bucket[(size_t)n * CAP + e];  // group-uniform
    if ((unsigned)s >= (unsigned)Nn) s = 0;
    if (act) acc += hl[(size_t)s * 7 + c];
  }
  float dd = cn > 0 ? (float)cn : 1.f;
  float v = act ? (acc / dd + hr[(size_t)n * 7 + c]) : -INFINITY;
  float mx = v;
  mx = fmaxf(mx, __shfl_xor(mx, 1, 8));
  mx = fmaxf(mx, __shfl_xor(mx, 2, 8));
  mx = fmaxf(mx, __shfl_xor(mx, 4, 8));
  float ex = act ? expf(v - mx) : 0.f;
  float s2 = ex;
  s2 += __shfl_xor(s2, 1, 8);
  s2 += __shfl_xor(s2, 2, 8);
  s2 += __shfl_xor(s2, 4, 8);
  float res = v - mx - logf(s2);
  if (act) out[(size_t)n * 7 + c] = res;
}

static inline size_t alignup(size_t v) { return (v + 255) & ~(size_t)255; }

extern "C" void kernel_launch(void* const* d_in, const int* in_sizes, int n_in,
                              void* d_out, int out_size, void* d_ws, size_t ws_size,
                              hipStream_t stream) {
  const int N = in_sizes[0] / 128;
  const int E = in_sizes[1] / 2;
  const int NB = (N + BINSZ - 1) / BINSZ;   // 782 bins
  const int Np = NB * BINSZ;                // padded node count
  const int NCH = (E + CH - 1) / CH;        // 98 chunks

  const float* x   = (const float*)d_in[0];
  const int*   ei  = (const int*)d_in[1];
  const float* W1l = (const float*)d_in[2];
  const float* W1r = (const float*)d_in[3];
  const float* b1  = (const float*)d_in[4];
  const float* W2l = (const float*)d_in[5];
  const float* W2r = (const float*)d_in[6];
  const float* b2  = (const float*)d_in[7];
  float* out = (float*)d_out;

  // workspace carve (~78 MB)
  char* p = (char*)d_ws;
  int* hist    = (int*)p;            p += alignup((size_t)NB * NCH * 4);
  int* tot     = (int*)p;            p += alignup((size_t)NB * 4);
  int* binbase = (int*)p;            p += alignup((size_t)(NB + 1) * 4);
  unsigned int* part = (unsigned int*)p; p += alignup((size_t)E * 4);
  int* cnt    = (int*)p;             p += alignup((size_t)Np * 4);
  int* bucket = (int*)p;             p += alignup((size_t)Np * CAP * 4);
  unsigned short* xl    = (unsigned short*)p; p += alignup((size_t)N * 64 * 2);
  unsigned short* hroot = (unsigned short*)p; p += alignup((size_t)N * 64 * 2);
  unsigned short* hbuf  = (unsigned short*)p; p += alignup((size_t)N * 64 * 2);
  float* hl  = (float*)p;            p += alignup((size_t)N * 7 * 4);
  float* hr  = (float*)p;            p += alignup((size_t)N * 7 * 4);

  dim3 b256(256);
  k_hist<<<dim3(NCH), b256, 0, stream>>>(ei, hist, E, NB, NCH);
  k_scanA<<<dim3((NB + 3) / 4), b256, 0, stream>>>(hist, tot, NB, NCH);
  k_scanB<<<dim3(1), dim3(64), 0, stream>>>(tot, binbase, NB);
  k_scat<<<dim3(NCH), b256, 0, stream>>>(ei, hist, binbase, part, E, NB, NCH);
  k_bucketB<<<dim3(NB), b256, 0, stream>>>(binbase, part, cnt, bucket);
  k_gemm1<<<dim3((N + 63) / 64), dim3(512), 0, stream>>>(x, W1l, W1r, b1, xl, hroot, N);
  k_agg1<<<dim3(2048), b256, 0, stream>>>(cnt, bucket, xl, hroot, hbuf, N);
  k_gemm2<<<dim3((N + 127) / 128), dim3(128), 0, stream>>>(hbuf, W2l, W2r, b2, hl, hr, N);
  const int waves_out = (N + 7) / 8;
  k_out<<<dim3((waves_out + 3) / 4), b256, 0, stream>>>(cnt, bucket, hl, hr, out, N);
}

// Round 10
// 282.639 us; speedup vs baseline: 2.4302x; 1.1641x over previous
//
#include <hip/hip_runtime.h>
#include <cstdint>
#include <cstddef>

// GraphSAGE 2-layer fused pipeline, MI355X.
// Identity: segment_mean(x[src]) @ W == segment_mean((x@W)[src]) -> GEMM before gather.
// Inputs f32, output f32. Intermediates bf16-stored / f32-computed.
// R10: k_gemm1 -> MFMA (16x16x32 bf16). R9's VALU version was LDS-BW bound
//     (wave-uniform ds_read_b128 is not a free broadcast: 1024B/inst; CU LDS
//     demand 2x per-SIMD VALU demand -> measured 2x shortfall). Now W1l|W1r
//     concatenated to a 128x128 panel, pre-swizzled once into B-frag order
//     (k_wprep), hot loop = 32 MFMA + 32 contiguous ds_read_b128 per wave.
//     Verified layouts: A[m=lane&15][k=quad*8+j]; C col=lane&15,row=quad*4+reg.

#define CAP 64
#define BINSZ 128        // nodes per bin (dst >> 7)
#define CH 16384         // edges per chunk block

typedef __attribute__((ext_vector_type(8))) short bf16x8v;
typedef __attribute__((ext_vector_type(4))) float f32x4v;

__device__ __forceinline__ float bf2f(unsigned short u) {
  return __uint_as_float(((unsigned int)u) << 16);
}
__device__ __forceinline__ unsigned short f2bf(float f) {
  unsigned int x = __float_as_uint(f);
  unsigned int r = (x + 0x7fffu + ((x >> 16) & 1u)) >> 16;  // RNE
  return (unsigned short)r;
}

// ---------------- pass 1: per-chunk histogram over dst bins (no global atomics) ----------------
__global__ __launch_bounds__(256) void k_hist(const int* __restrict__ ei,
                                              int* __restrict__ hist,
                                              int E, int NB, int NCH) {
  __shared__ int lcnt[1024];
  const int c = blockIdx.x, t = threadIdx.x;
  for (int i = t; i < NB; i += 256) lcnt[i] = 0;
  __syncthreads();
  const int base = c * CH;
  const int end = min(base + CH, E);
  for (int e = base + t; e < end; e += 256) {
    int d = ei[E + e];
    atomicAdd(&lcnt[d >> 7], 1);  // LDS atomic
  }
  __syncthreads();
  for (int i = t; i < NB; i += 256) hist[(size_t)i * NCH + c] = lcnt[i];
}

// ---------------- pass 2a: per-bin exclusive scan over chunks (1 wave/bin) ----------------
__global__ __launch_bounds__(256) void k_scanA(int* __restrict__ hist,
                                               int* __restrict__ tot,
                                               int NB, int NCH) {
  const int lane = threadIdx.x & 63;
  const int bin = blockIdx.x * 4 + (threadIdx.x >> 6);
  if (bin >= NB) return;
  int* h = hist + (size_t)bin * NCH;
  int carry = 0;
  for (int base = 0; base < NCH; base += 64) {
    int i = base + lane;
    int v = (i < NCH) ? h[i] : 0;
    int incl = v;
    #pragma unroll
    for (int d = 1; d < 64; d <<= 1) {
      int t = __shfl_up(incl, d, 64);
      if (lane >= d) incl += t;
    }
    if (i < NCH) h[i] = carry + incl - v;  // exclusive prefix within bin
    carry += __shfl(incl, 63, 64);
  }
  if (lane == 0) tot[bin] = carry;
}

// ---------------- pass 2b: scan bin totals -> binbase (1 wave) ----------------
__global__ __launch_bounds__(64) void k_scanB(const int* __restrict__ tot,
                                              int* __restrict__ binbase, int NB) {
  const int lane = threadIdx.x;
  int carry = 0;
  for (int base = 0; base < NB; base += 64) {
    int i = base + lane;
    int v = (i < NB) ? tot[i] : 0;
    int incl = v;
    #pragma unroll
    for (int d = 1; d < 64; d <<= 1) {
      int t = __shfl_up(incl, d, 64);
      if (lane >= d) incl += t;
    }
    if (i < NB) binbase[i] = carry + incl - v;
    carry += __shfl(incl, 63, 64);
  }
  if (lane == 0) binbase[NB] = carry;  // == E
}

// ---------------- pass 3: scatter edges to bin-sorted array (LDS cursors only) ----------------
__global__ __launch_bounds__(256) void k_scat(const int* __restrict__ ei,
                                              const int* __restrict__ hist,
                                              const int* __restrict__ binbase,
                                              unsigned int* __restrict__ part,
                                              int E, int NB, int NCH) {
  __shared__ int lcur[1024];
  const int c = blockIdx.x, t = threadIdx.x;
  for (int i = t; i < NB; i += 256)
    lcur[i] = hist[(size_t)i * NCH + c] + binbase[i];
  __syncthreads();
  const int base = c * CH;
  const int end = min(base + CH, E);
  for (int e = base + t; e < end; e += 256) {
    int s = ei[e];        // src < 2^17
    int d = ei[E + e];    // dst
    int bin = d >> 7;
    int pos = atomicAdd(&lcur[bin], 1);  // LDS atomic; positions exact
    part[pos] = (unsigned)s | ((unsigned)(d & 127) << 17);
  }
}

// ---------------- pass 4: per-bin bucket build in LDS, coalesced writeout ----------------
__global__ __launch_bounds__(256) void k_bucketB(const int* __restrict__ binbase,
                                                 const unsigned int* __restrict__ part,
                                                 int* __restrict__ cnt,
                                                 int* __restrict__ bucket) {
  __shared__ int lbkt[BINSZ * CAP];  // 32 KB
  __shared__ int ldeg[BINSZ];
  const int b = blockIdx.x, t = threadIdx.x;
  if (t < BINSZ) ldeg[t] = 0;
  __syncthreads();
  const int e0 = binbase[b], e1 = binbase[b + 1];
  for (int i = e0 + t; i < e1; i += 256) {
    unsigned rec = part[i];
    int loc = rec >> 17;
    int p = atomicAdd(&ldeg[loc], 1);
    if (p < CAP) lbkt[loc * CAP + p] = (int)(rec & 0x1FFFFu);
  }
  __syncthreads();
  if (t < BINSZ) cnt[b * BINSZ + t] = ldeg[t];
  const int4* s4 = (const int4*)lbkt;
  int4* d4 = (int4*)(bucket + (size_t)b * BINSZ * CAP);
  #pragma unroll 2
  for (int i = t; i < BINSZ * CAP / 4; i += 256) d4[i] = s4[i];
}

// ---------------- weight prep: swizzle [W1l|W1r] into B-fragment order, bf16 ----------------
// B-frag for mfma_f32_16x16x32_bf16: lane holds B[k=quad*8+j][n=lane&15].
// wswz[((t4*8 + c)*64 + lane)*8 + j] = bf16(Wc[t4*32 + quad*8 + j][c*16 + (lane&15)])
__global__ __launch_bounds__(256) void k_wprep(const float* __restrict__ W1l,
                                               const float* __restrict__ W1r,
                                               unsigned short* __restrict__ wswz) {
  int idx = blockIdx.x * 256 + threadIdx.x;  // [0, 16384)
  int j = idx & 7;
  int lane = (idx >> 3) & 63;
  int c = (idx >> 9) & 7;
  int t4 = idx >> 12;
  int kk = t4 * 32 + (lane >> 4) * 8 + j;
  int nn = c * 16 + (lane & 15);
  float v = (nn < 64) ? W1l[kk * 64 + nn] : W1r[kk * 64 + (nn - 64)];
  wswz[idx] = f2bf(v);
}

// ---------------- layer-1 GEMM via MFMA: [xl | hroot] = x @ [W1l | W1r] (+b1) ----------------
// 256 thr = 4 waves; wave computes 16 rows x 128 cols. Grid = ceil(N/64).
__global__ __launch_bounds__(256) void k_gemm1(
    const float* __restrict__ x,
    const unsigned short* __restrict__ wswz,
    const float* __restrict__ b1,
    unsigned short* __restrict__ xl,
    unsigned short* __restrict__ hroot,
    int Nn) {
  __shared__ unsigned short Bsw[16384];  // 32 KB
  const int t = threadIdx.x;
  {
    const uint4* src = (const uint4*)wswz;
    uint4* dst = (uint4*)Bsw;
    #pragma unroll
    for (int i = 0; i < 8; ++i) dst[t + i * 256] = src[t + i * 256];
  }
  __syncthreads();

  const int lane = t & 63;
  const int wid = t >> 6;
  const int quad = lane >> 4;
  const int m = lane & 15;
  const int rowA = blockIdx.x * 64 + wid * 16 + m;       // A-operand row for this lane
  const float* xrow = x + (size_t)min(rowA, Nn - 1) * 128;

  f32x4v acc[8];
  #pragma unroll
  for (int c = 0; c < 8; ++c) acc[c] = (f32x4v){0.f, 0.f, 0.f, 0.f};

  #pragma unroll
  for (int t4 = 0; t4 < 4; ++t4) {
    const int koff = t4 * 32 + quad * 8;
    float4 a0 = *(const float4*)(xrow + koff);
    float4 a1 = *(const float4*)(xrow + koff + 4);
    bf16x8v af;
    af[0] = (short)f2bf(a0.x); af[1] = (short)f2bf(a0.y);
    af[2] = (short)f2bf(a0.z); af[3] = (short)f2bf(a0.w);
    af[4] = (short)f2bf(a1.x); af[5] = (short)f2bf(a1.y);
    af[6] = (short)f2bf(a1.z); af[7] = (short)f2bf(a1.w);
    #pragma unroll
    for (int c = 0; c < 8; ++c) {
      const bf16x8v bf_ = *(const bf16x8v*)&Bsw[(((t4 * 8 + c) * 64 + lane)) << 3];
      acc[c] = __builtin_amdgcn_mfma_f32_16x16x32_bf16(af, bf_, acc[c], 0, 0, 0);
    }
  }

  // C/D layout: col = lane&15 (within 16-tile), row = quad*4 + reg
  const int rbase = blockIdx.x * 64 + wid * 16 + quad * 4;
  #pragma unroll
  for (int c = 0; c < 8; ++c) {
    const int col = c * 16 + m;        // 0..127
    #pragma unroll
    for (int i = 0; i < 4; ++i) {
      const int r = rbase + i;
      if (r < Nn) {
        if (c < 4) xl[(size_t)r * 64 + col] = f2bf(acc[c][i]);
        else       hroot[(size_t)r * 64 + (col - 64)] = f2bf(acc[c][i] + b1[col - 64]);
      }
    }
  }
}

// ---------------- layer-1 aggregate: h = relu(mean_nb(xl) + hroot), wave per node ----------------
__global__ __launch_bounds__(256) void k_agg1(
    const int* __restrict__ cnt, const int* __restrict__ bucket,
    const unsigned short* __restrict__ xl, const unsigned short* __restrict__ hroot,
    unsigned short* __restrict__ hbuf, int Nn) {
  const int lane = threadIdx.x & 63;
  const int gw = blockIdx.x * (blockDim.x >> 6) + (threadIdx.x >> 6);
  const int nw = gridDim.x * (blockDim.x >> 6);
  for (int n = gw; n < Nn; n += nw) {
    int c = cnt[n];
    int m = c < CAP ? c : CAP;
    int sidx = (lane < m) ? bucket[(size_t)n * CAP + lane] : 0;
    if ((unsigned)sidx >= (unsigned)Nn) sidx = 0;  // firewall
    float acc = 0.f;
    int i = 0;
    for (; i + 4 <= m; i += 4) {
      int s0 = __shfl(sidx, i, 64);
      int s1 = __shfl(sidx, i + 1, 64);
      int s2 = __shfl(sidx, i + 2, 64);
      int s3 = __shfl(sidx, i + 3, 64);
      float v0 = bf2f(xl[(size_t)s0 * 64 + lane]);
      float v1 = bf2f(xl[(size_t)s1 * 64 + lane]);
      float v2 = bf2f(xl[(size_t)s2 * 64 + lane]);
      float v3 = bf2f(xl[(size_t)s3 * 64 + lane]);
      acc += (v0 + v1) + (v2 + v3);
    }
    for (; i < m; ++i) {
      int s = __shfl(sidx, i, 64);
      acc += bf2f(xl[(size_t)s * 64 + lane]);
    }
    float dd = c > 0 ? (float)c : 1.f;
    float hv = acc / dd + bf2f(hroot[(size_t)n * 64 + lane]);
    hbuf[(size_t)n * 64 + lane] = f2bf(fmaxf(hv, 0.f));
  }
}

// ---------------- layer-2 GEMMs: hl = h@W2l, hr = h@W2r + b2 ; thread per row ----------------
__global__ __launch_bounds__(128) void k_gemm2(
    const unsigned short* __restrict__ hbuf,
    const float* __restrict__ W2l, const float* __restrict__ W2r,
    const float* __restrict__ b2,
    float* __restrict__ hl, float* __restrict__ hr, int Nn) {
  __shared__ float tile[128 * 65];  // +1 pad: conflict-free column reads
  const int t = threadIdx.x;
  const int rowbase = blockIdx.x * 128;
  for (int idx = t; idx < 128 * 64; idx += 128) {
    int r = idx >> 6, k = idx & 63;
    int n = rowbase + r;
    tile[r * 65 + k] = (n < Nn) ? bf2f(hbuf[(size_t)n * 64 + k]) : 0.f;
  }
  __syncthreads();
  int n = rowbase + t;
  if (n >= Nn) return;
  float al[7] = {0, 0, 0, 0, 0, 0, 0};
  float ar[7] = {0, 0, 0, 0, 0, 0, 0};
  for (int k = 0; k < 64; ++k) {
    float hv = tile[t * 65 + k];
    #pragma unroll
    for (int c = 0; c < 7; ++c) {
      al[c] = fmaf(hv, W2l[k * 7 + c], al[c]);
      ar[c] = fmaf(hv, W2r[k * 7 + c], ar[c]);
    }
  }
  #pragma unroll
  for (int c = 0; c < 7; ++c) {
    hl[(size_t)n * 7 + c] = al[c];
    hr[(size_t)n * 7 + c] = ar[c] + b2[c];
  }
}

// ---------------- layer-2 aggregate + log_softmax; 8 nodes/wave, 8 lanes/node ----------------
__global__ __launch_bounds__(256) void k_out(
    const int* __restrict__ cnt, const int* __restrict__ bucket,
    const float* __restrict__ hl, const float* __restrict__ hr,
    float* __restrict__ out, int Nn) {
  const int lane = threadIdx.x & 63;
  const int c = lane & 7;
  const int sub = lane >> 3;
  const int gw = blockIdx.x * (blockDim.x >> 6) + (threadIdx.x >> 6);
  const int n = gw * 8 + sub;
  if (n >= Nn) return;
  int cn = cnt[n];
  int m = cn < CAP ? cn : CAP;
  const bool act = (c < 7);
  float acc = 0.f;
  for (int e = 0; e < m; ++e) {
    int s = bucket[(size_t)n * CAP + e];  // group-uniform
    if ((unsigned)s >= (unsigned)Nn) s = 0;
    if (act) acc += hl[(size_t)s * 7 + c];
  }
  float dd = cn > 0 ? (float)cn : 1.f;
  float v = act ? (acc / dd + hr[(size_t)n * 7 + c]) : -INFINITY;
  float mx = v;
  mx = fmaxf(mx, __shfl_xor(mx, 1, 8));
  mx = fmaxf(mx, __shfl_xor(mx, 2, 8));
  mx = fmaxf(mx, __shfl_xor(mx, 4, 8));
  float ex = act ? expf(v - mx) : 0.f;
  float s2 = ex;
  s2 += __shfl_xor(s2, 1, 8);
  s2 += __shfl_xor(s2, 2, 8);
  s2 += __shfl_xor(s2, 4, 8);
  float res = v - mx - logf(s2);
  if (act) out[(size_t)n * 7 + c] = res;
}

static inline size_t alignup(size_t v) { return (v + 255) & ~(size_t)255; }

extern "C" void kernel_launch(void* const* d_in, const int* in_sizes, int n_in,
                              void* d_out, int out_size, void* d_ws, size_t ws_size,
                              hipStream_t stream) {
  const int N = in_sizes[0] / 128;
  const int E = in_sizes[1] / 2;
  const int NB = (N + BINSZ - 1) / BINSZ;   // 782 bins
  const int Np = NB * BINSZ;                // padded node count
  const int NCH = (E + CH - 1) / CH;        // 98 chunks

  const float* x   = (const float*)d_in[0];
  const int*   ei  = (const int*)d_in[1];
  const float* W1l = (const float*)d_in[2];
  const float* W1r = (const float*)d_in[3];
  const float* b1  = (const float*)d_in[4];
  const float* W2l = (const float*)d_in[5];
  const float* W2r = (const float*)d_in[6];
  const float* b2  = (const float*)d_in[7];
  float* out = (float*)d_out;

  // workspace carve (~78 MB)
  char* p = (char*)d_ws;
  int* hist    = (int*)p;            p += alignup((size_t)NB * NCH * 4);
  int* tot     = (int*)p;            p += alignup((size_t)NB * 4);
  int* binbase = (int*)p;            p += alignup((size_t)(NB + 1) * 4);
  unsigned int* part = (unsigned int*)p; p += alignup((size_t)E * 4);
  int* cnt    = (int*)p;             p += alignup((size_t)Np * 4);
  int* bucket = (int*)p;             p += alignup((size_t)Np * CAP * 4);
  unsigned short* wswz = (unsigned short*)p; p += alignup((size_t)16384 * 2);
  unsigned short* xl    = (unsigned short*)p; p += alignup((size_t)N * 64 * 2);
  unsigned short* hroot = (unsigned short*)p; p += alignup((size_t)N * 64 * 2);
  unsigned short* hbuf  = (unsigned short*)p; p += alignup((size_t)N * 64 * 2);
  float* hl  = (float*)p;            p += alignup((size_t)N * 7 * 4);
  float* hr  = (float*)p;            p += alignup((size_t)N * 7 * 4);

  dim3 b256(256);
  k_hist<<<dim3(NCH), b256, 0, stream>>>(ei, hist, E, NB, NCH);
  k_scanA<<<dim3((NB + 3) / 4), b256, 0, stream>>>(hist, tot, NB, NCH);
  k_scanB<<<dim3(1), dim3(64), 0, stream>>>(tot, binbase, NB);
  k_scat<<<dim3(NCH), b256, 0, stream>>>(ei, hist, binbase, part, E, NB, NCH);
  k_bucketB<<<dim3(NB), b256, 0, stream>>>(binbase, part, cnt, bucket);
  k_wprep<<<dim3(64), b256, 0, stream>>>(W1l, W1r, wswz);
  k_gemm1<<<dim3((N + 63) / 64), b256, 0, stream>>>(x, wswz, b1, xl, hroot, N);
  k_agg1<<<dim3(2048), b256, 0, stream>>>(cnt, bucket, xl, hroot, hbuf, N);
  k_gemm2<<<dim3((N + 127) / 128), dim3(128), 0, stream>>>(hbuf, W2l, W2r, b2, hl, hr, N);
  const int waves_out = (N + 7) / 8;
  k_out<<<dim3((waves_out + 3) / 4), b256, 0, stream>>>(cnt, bucket, hl, hr, out, N);
}

// Round 11
// 281.336 us; speedup vs baseline: 2.4415x; 1.0046x over previous
//
#include <hip/hip_runtime.h>
#include <cstdint>
#include <cstddef>

// GraphSAGE 2-layer fused pipeline, MI355X.
// Identity: segment_mean(x[src]) @ W == segment_mean((x@W)[src]) -> GEMM before gather.
// Inputs f32, output f32. Intermediates bf16-stored / f32-computed.
// R11: k_agg1 gather restructured for 2x memory-level parallelism: lanes 0-31
//     take even edges / 32-63 odd edges, each lane loads a uint (2 bf16 cols),
//     so one global_load_dword covers TWO xl rows (256B); per-node load chain
//     halves (16->8 loads). shfl_xor(32) merges halves; lanes<32 write packed
//     bf16x2. R10 counters showed agg1 latency-bound: HBM 28%, VALU 42%, occ 66%.

#define CAP 64
#define BINSZ 128        // nodes per bin (dst >> 7)
#define CH 16384         // edges per chunk block

typedef __attribute__((ext_vector_type(8))) short bf16x8v;
typedef __attribute__((ext_vector_type(4))) float f32x4v;

__device__ __forceinline__ float bf2f(unsigned short u) {
  return __uint_as_float(((unsigned int)u) << 16);
}
__device__ __forceinline__ unsigned short f2bf(float f) {
  unsigned int x = __float_as_uint(f);
  unsigned int r = (x + 0x7fffu + ((x >> 16) & 1u)) >> 16;  // RNE
  return (unsigned short)r;
}

// ---------------- pass 1: per-chunk histogram over dst bins (no global atomics) ----------------
__global__ __launch_bounds__(256) void k_hist(const int* __restrict__ ei,
                                              int* __restrict__ hist,
                                              int E, int NB, int NCH) {
  __shared__ int lcnt[1024];
  const int c = blockIdx.x, t = threadIdx.x;
  for (int i = t; i < NB; i += 256) lcnt[i] = 0;
  __syncthreads();
  const int base = c * CH;
  const int end = min(base + CH, E);
  for (int e = base + t; e < end; e += 256) {
    int d = ei[E + e];
    atomicAdd(&lcnt[d >> 7], 1);  // LDS atomic
  }
  __syncthreads();
  for (int i = t; i < NB; i += 256) hist[(size_t)i * NCH + c] = lcnt[i];
}

// ---------------- pass 2a: per-bin exclusive scan over chunks (1 wave/bin) ----------------
__global__ __launch_bounds__(256) void k_scanA(int* __restrict__ hist,
                                               int* __restrict__ tot,
                                               int NB, int NCH) {
  const int lane = threadIdx.x & 63;
  const int bin = blockIdx.x * 4 + (threadIdx.x >> 6);
  if (bin >= NB) return;
  int* h = hist + (size_t)bin * NCH;
  int carry = 0;
  for (int base = 0; base < NCH; base += 64) {
    int i = base + lane;
    int v = (i < NCH) ? h[i] : 0;
    int incl = v;
    #pragma unroll
    for (int d = 1; d < 64; d <<= 1) {
      int t = __shfl_up(incl, d, 64);
      if (lane >= d) incl += t;
    }
    if (i < NCH) h[i] = carry + incl - v;  // exclusive prefix within bin
    carry += __shfl(incl, 63, 64);
  }
  if (lane == 0) tot[bin] = carry;
}

// ---------------- pass 2b: scan bin totals -> binbase (1 wave) ----------------
__global__ __launch_bounds__(64) void k_scanB(const int* __restrict__ tot,
                                              int* __restrict__ binbase, int NB) {
  const int lane = threadIdx.x;
  int carry = 0;
  for (int base = 0; base < NB; base += 64) {
    int i = base + lane;
    int v = (i < NB) ? tot[i] : 0;
    int incl = v;
    #pragma unroll
    for (int d = 1; d < 64; d <<= 1) {
      int t = __shfl_up(incl, d, 64);
      if (lane >= d) incl += t;
    }
    if (i < NB) binbase[i] = carry + incl - v;
    carry += __shfl(incl, 63, 64);
  }
  if (lane == 0) binbase[NB] = carry;  // == E
}

// ---------------- pass 3: scatter edges to bin-sorted array (LDS cursors only) ----------------
__global__ __launch_bounds__(256) void k_scat(const int* __restrict__ ei,
                                              const int* __restrict__ hist,
                                              const int* __restrict__ binbase,
                                              unsigned int* __restrict__ part,
                                              int E, int NB, int NCH) {
  __shared__ int lcur[1024];
  const int c = blockIdx.x, t = threadIdx.x;
  for (int i = t; i < NB; i += 256)
    lcur[i] = hist[(size_t)i * NCH + c] + binbase[i];
  __syncthreads();
  const int base = c * CH;
  const int end = min(base + CH, E);
  for (int e = base + t; e < end; e += 256) {
    int s = ei[e];        // src < 2^17
    int d = ei[E + e];    // dst
    int bin = d >> 7;
    int pos = atomicAdd(&lcur[bin], 1);  // LDS atomic; positions exact
    part[pos] = (unsigned)s | ((unsigned)(d & 127) << 17);
  }
}

// ---------------- pass 4: per-bin bucket build in LDS, coalesced writeout ----------------
__global__ __launch_bounds__(256) void k_bucketB(const int* __restrict__ binbase,
                                                 const unsigned int* __restrict__ part,
                                                 int* __restrict__ cnt,
                                                 int* __restrict__ bucket) {
  __shared__ int lbkt[BINSZ * CAP];  // 32 KB
  __shared__ int ldeg[BINSZ];
  const int b = blockIdx.x, t = threadIdx.x;
  if (t < BINSZ) ldeg[t] = 0;
  __syncthreads();
  const int e0 = binbase[b], e1 = binbase[b + 1];
  for (int i = e0 + t; i < e1; i += 256) {
    unsigned rec = part[i];
    int loc = rec >> 17;
    int p = atomicAdd(&ldeg[loc], 1);
    if (p < CAP) lbkt[loc * CAP + p] = (int)(rec & 0x1FFFFu);
  }
  __syncthreads();
  if (t < BINSZ) cnt[b * BINSZ + t] = ldeg[t];
  const int4* s4 = (const int4*)lbkt;
  int4* d4 = (int4*)(bucket + (size_t)b * BINSZ * CAP);
  #pragma unroll 2
  for (int i = t; i < BINSZ * CAP / 4; i += 256) d4[i] = s4[i];
}

// ---------------- weight prep: swizzle [W1l|W1r] into B-fragment order, bf16 ----------------
__global__ __launch_bounds__(256) void k_wprep(const float* __restrict__ W1l,
                                               const float* __restrict__ W1r,
                                               unsigned short* __restrict__ wswz) {
  int idx = blockIdx.x * 256 + threadIdx.x;  // [0, 16384)
  int j = idx & 7;
  int lane = (idx >> 3) & 63;
  int c = (idx >> 9) & 7;
  int t4 = idx >> 12;
  int kk = t4 * 32 + (lane >> 4) * 8 + j;
  int nn = c * 16 + (lane & 15);
  float v = (nn < 64) ? W1l[kk * 64 + nn] : W1r[kk * 64 + (nn - 64)];
  wswz[idx] = f2bf(v);
}

// ---------------- layer-1 GEMM via MFMA: [xl | hroot] = x @ [W1l | W1r] (+b1) ----------------
__global__ __launch_bounds__(256) void k_gemm1(
    const float* __restrict__ x,
    const unsigned short* __restrict__ wswz,
    const float* __restrict__ b1,
    unsigned short* __restrict__ xl,
    unsigned short* __restrict__ hroot,
    int Nn) {
  __shared__ unsigned short Bsw[16384];  // 32 KB
  const int t = threadIdx.x;
  {
    const uint4* src = (const uint4*)wswz;
    uint4* dst = (uint4*)Bsw;
    #pragma unroll
    for (int i = 0; i < 8; ++i) dst[t + i * 256] = src[t + i * 256];
  }
  __syncthreads();

  const int lane = t & 63;
  const int wid = t >> 6;
  const int quad = lane >> 4;
  const int m = lane & 15;
  const int rowA = blockIdx.x * 64 + wid * 16 + m;
  const float* xrow = x + (size_t)min(rowA, Nn - 1) * 128;

  f32x4v acc[8];
  #pragma unroll
  for (int c = 0; c < 8; ++c) acc[c] = (f32x4v){0.f, 0.f, 0.f, 0.f};

  #pragma unroll
  for (int t4 = 0; t4 < 4; ++t4) {
    const int koff = t4 * 32 + quad * 8;
    float4 a0 = *(const float4*)(xrow + koff);
    float4 a1 = *(const float4*)(xrow + koff + 4);
    bf16x8v af;
    af[0] = (short)f2bf(a0.x); af[1] = (short)f2bf(a0.y);
    af[2] = (short)f2bf(a0.z); af[3] = (short)f2bf(a0.w);
    af[4] = (short)f2bf(a1.x); af[5] = (short)f2bf(a1.y);
    af[6] = (short)f2bf(a1.z); af[7] = (short)f2bf(a1.w);
    #pragma unroll
    for (int c = 0; c < 8; ++c) {
      const bf16x8v bf_ = *(const bf16x8v*)&Bsw[(((t4 * 8 + c) * 64 + lane)) << 3];
      acc[c] = __builtin_amdgcn_mfma_f32_16x16x32_bf16(af, bf_, acc[c], 0, 0, 0);
    }
  }

  const int rbase = blockIdx.x * 64 + wid * 16 + quad * 4;
  #pragma unroll
  for (int c = 0; c < 8; ++c) {
    const int col = c * 16 + m;
    #pragma unroll
    for (int i = 0; i < 4; ++i) {
      const int r = rbase + i;
      if (r < Nn) {
        if (c < 4) xl[(size_t)r * 64 + col] = f2bf(acc[c][i]);
        else       hroot[(size_t)r * 64 + (col - 64)] = f2bf(acc[c][i] + b1[col - 64]);
      }
    }
  }
}

// ---------------- layer-1 aggregate: h = relu(mean_nb(xl) + hroot) ----------------
// Wave per node; lanes 0-31 handle even edges, 32-63 odd edges; 1 dword load = 2 rows.
__global__ __launch_bounds__(256) void k_agg1(
    const int* __restrict__ cnt, const int* __restrict__ bucket,
    const unsigned int* __restrict__ xl32, const unsigned int* __restrict__ hroot32,
    unsigned int* __restrict__ hbuf32, int Nn) {
  const int lane = threadIdx.x & 63;
  const int p = lane & 31;      // uint column (covers bf16 cols 2p, 2p+1)
  const int sel = lane >> 5;    // 0: even edges, 1: odd edges
  const int gw = blockIdx.x * (blockDim.x >> 6) + (threadIdx.x >> 6);
  const int nw = gridDim.x * (blockDim.x >> 6);
  for (int n = gw; n < Nn; n += nw) {
    int c = cnt[n];
    int m = c < CAP ? c : CAP;
    int sidx = (lane < m) ? bucket[(size_t)n * CAP + lane] : 0;
    if ((unsigned)sidx >= (unsigned)Nn) sidx = 0;  // firewall
    float accLo = 0.f, accHi = 0.f;
    int i = 0;
    for (; i + 8 <= m; i += 8) {   // 8 edges per iter, 4 loads in flight
      int r0 = __shfl(sidx, i + 0 + sel, 64);
      int r1 = __shfl(sidx, i + 2 + sel, 64);
      int r2 = __shfl(sidx, i + 4 + sel, 64);
      int r3 = __shfl(sidx, i + 6 + sel, 64);
      unsigned u0 = xl32[(size_t)r0 * 32 + p];
      unsigned u1 = xl32[(size_t)r1 * 32 + p];
      unsigned u2 = xl32[(size_t)r2 * 32 + p];
      unsigned u3 = xl32[(size_t)r3 * 32 + p];
      accLo += (__uint_as_float(u0 << 16) + __uint_as_float(u1 << 16))
             + (__uint_as_float(u2 << 16) + __uint_as_float(u3 << 16));
      accHi += (__uint_as_float(u0 & 0xFFFF0000u) + __uint_as_float(u1 & 0xFFFF0000u))
             + (__uint_as_float(u2 & 0xFFFF0000u) + __uint_as_float(u3 & 0xFFFF0000u));
    }
    for (; i < m; i += 2) {        // tail pairs (with odd-m guard)
      int e = i + sel;
      int esafe = e < m ? e : (m - 1);
      int r = __shfl(sidx, esafe, 64);
      unsigned u = xl32[(size_t)r * 32 + p];
      if (e < m) {
        accLo += __uint_as_float(u << 16);
        accHi += __uint_as_float(u & 0xFFFF0000u);
      }
    }
    accLo += __shfl_xor(accLo, 32, 64);
    accHi += __shfl_xor(accHi, 32, 64);
    if (sel == 0) {
      float dd = c > 0 ? (float)c : 1.f;
      unsigned hu = hroot32[(size_t)n * 32 + p];
      float h0 = fmaxf(accLo / dd + __uint_as_float(hu << 16), 0.f);
      float h1 = fmaxf(accHi / dd + __uint_as_float(hu & 0xFFFF0000u), 0.f);
      hbuf32[(size_t)n * 32 + p] = (unsigned)f2bf(h0) | ((unsigned)f2bf(h1) << 16);
    }
  }
}

// ---------------- layer-2 GEMMs: hl = h@W2l, hr = h@W2r + b2 ; thread per row ----------------
__global__ __launch_bounds__(128) void k_gemm2(
    const unsigned short* __restrict__ hbuf,
    const float* __restrict__ W2l, const float* __restrict__ W2r,
    const float* __restrict__ b2,
    float* __restrict__ hl, float* __restrict__ hr, int Nn) {
  __shared__ float tile[128 * 65];  // +1 pad: conflict-free column reads
  const int t = threadIdx.x;
  const int rowbase = blockIdx.x * 128;
  for (int idx = t; idx < 128 * 64; idx += 128) {
    int r = idx >> 6, k = idx & 63;
    int n = rowbase + r;
    tile[r * 65 + k] = (n < Nn) ? bf2f(hbuf[(size_t)n * 64 + k]) : 0.f;
  }
  __syncthreads();
  int n = rowbase + t;
  if (n >= Nn) return;
  float al[7] = {0, 0, 0, 0, 0, 0, 0};
  float ar[7] = {0, 0, 0, 0, 0, 0, 0};
  for (int k = 0; k < 64; ++k) {
    float hv = tile[t * 65 + k];
    #pragma unroll
    for (int c = 0; c < 7; ++c) {
      al[c] = fmaf(hv, W2l[k * 7 + c], al[c]);
      ar[c] = fmaf(hv, W2r[k * 7 + c], ar[c]);
    }
  }
  #pragma unroll
  for (int c = 0; c < 7; ++c) {
    hl[(size_t)n * 7 + c] = al[c];
    hr[(size_t)n * 7 + c] = ar[c] + b2[c];
  }
}

// ---------------- layer-2 aggregate + log_softmax; 8 nodes/wave, 8 lanes/node ----------------
__global__ __launch_bounds__(256) void k_out(
    const int* __restrict__ cnt, const int* __restrict__ bucket,
    const float* __restrict__ hl, const float* __restrict__ hr,
    float* __restrict__ out, int Nn) {
  const int lane = threadIdx.x & 63;
  const int c = lane & 7;
  const int sub = lane >> 3;
  const int gw = blockIdx.x * (blockDim.x >> 6) + (threadIdx.x >> 6);
  const int n = gw * 8 + sub;
  if (n >= Nn) return;
  int cn = cnt[n];
  int m = cn < CAP ? cn : CAP;
  const bool act = (c < 7);
  float acc = 0.f;
  for (int e = 0; e < m; ++e) {
    int s = bucket[(size_t)n * CAP + e];  // group-uniform
    if ((unsigned)s >= (unsigned)Nn) s = 0;
    if (act) acc += hl[(size_t)s * 7 + c];
  }
  float dd = cn > 0 ? (float)cn : 1.f;
  float v = act ? (acc / dd + hr[(size_t)n * 7 + c]) : -INFINITY;
  float mx = v;
  mx = fmaxf(mx, __shfl_xor(mx, 1, 8));
  mx = fmaxf(mx, __shfl_xor(mx, 2, 8));
  mx = fmaxf(mx, __shfl_xor(mx, 4, 8));
  float ex = act ? expf(v - mx) : 0.f;
  float s2 = ex;
  s2 += __shfl_xor(s2, 1, 8);
  s2 += __shfl_xor(s2, 2, 8);
  s2 += __shfl_xor(s2, 4, 8);
  float res = v - mx - logf(s2);
  if (act) out[(size_t)n * 7 + c] = res;
}

static inline size_t alignup(size_t v) { return (v + 255) & ~(size_t)255; }

extern "C" void kernel_launch(void* const* d_in, const int* in_sizes, int n_in,
                              void* d_out, int out_size, void* d_ws, size_t ws_size,
                              hipStream_t stream) {
  const int N = in_sizes[0] / 128;
  const int E = in_sizes[1] / 2;
  const int NB = (N + BINSZ - 1) / BINSZ;   // 782 bins
  const int Np = NB * BINSZ;                // padded node count
  const int NCH = (E + CH - 1) / CH;        // 98 chunks

  const float* x   = (const float*)d_in[0];
  const int*   ei  = (const int*)d_in[1];
  const float* W1l = (const float*)d_in[2];
  const float* W1r = (const float*)d_in[3];
  const float* b1  = (const float*)d_in[4];
  const float* W2l = (const float*)d_in[5];
  const float* W2r = (const float*)d_in[6];
  const float* b2  = (const float*)d_in[7];
  float* out = (float*)d_out;

  // workspace carve (~78 MB)
  char* p = (char*)d_ws;
  int* hist    = (int*)p;            p += alignup((size_t)NB * NCH * 4);
  int* tot     = (int*)p;            p += alignup((size_t)NB * 4);
  int* binbase = (int*)p;            p += alignup((size_t)(NB + 1) * 4);
  unsigned int* part = (unsigned int*)p; p += alignup((size_t)E * 4);
  int* cnt    = (int*)p;             p += alignup((size_t)Np * 4);
  int* bucket = (int*)p;             p += alignup((size_t)Np * CAP * 4);
  unsigned short* wswz = (unsigned short*)p; p += alignup((size_t)16384 * 2);
  unsigned short* xl    = (unsigned short*)p; p += alignup((size_t)N * 64 * 2);
  unsigned short* hroot = (unsigned short*)p; p += alignup((size_t)N * 64 * 2);
  unsigned short* hbuf  = (unsigned short*)p; p += alignup((size_t)N * 64 * 2);
  float* hl  = (float*)p;            p += alignup((size_t)N * 7 * 4);
  float* hr  = (float*)p;            p += alignup((size_t)N * 7 * 4);

  dim3 b256(256);
  k_hist<<<dim3(NCH), b256, 0, stream>>>(ei, hist, E, NB, NCH);
  k_scanA<<<dim3((NB + 3) / 4), b256, 0, stream>>>(hist, tot, NB, NCH);
  k_scanB<<<dim3(1), dim3(64), 0, stream>>>(tot, binbase, NB);
  k_scat<<<dim3(NCH), b256, 0, stream>>>(ei, hist, binbase, part, E, NB, NCH);
  k_bucketB<<<dim3(NB), b256, 0, stream>>>(binbase, part, cnt, bucket);
  k_wprep<<<dim3(64), b256, 0, stream>>>(W1l, W1r, wswz);
  k_gemm1<<<dim3((N + 63) / 64), b256, 0, stream>>>(x, wswz, b1, xl, hroot, N);
  k_agg1<<<dim3(2048), b256, 0, stream>>>(cnt, bucket,
      (const unsigned int*)xl, (const unsigned int*)hroot, (unsigned int*)hbuf, N);
  k_gemm2<<<dim3((N + 127) / 128), dim3(128), 0, stream>>>(hbuf, W2l, W2r, b2, hl, hr, N);
  const int waves_out = (N + 7) / 8;
  k_out<<<dim3((waves_out + 3) / 4), b256, 0, stream>>>(cnt, bucket, hl, hr, out, N);
}